// Round 4
// baseline (212.946 us; speedup 1.0000x reference)
//
#include <hip/hip_runtime.h>
#include <hip/hip_bf16.h>

#define DEVI __device__ __forceinline__

typedef unsigned short u16;
typedef __bf16 bf16x8 __attribute__((ext_vector_type(8)));
typedef float f32x4 __attribute__((ext_vector_type(4)));

constexpr int Bn = 2, Cn = 1024, Ln = 2048, Hn = 16, Dn = 64;

DEVI u16 f2bfu(float f) { return __builtin_bit_cast(u16, __float2bfloat16(f)); }
DEVI float bfu2f(u16 u) { return __bfloat162float(__builtin_bit_cast(__hip_bfloat16, u)); }
DEVI f32x4 mfma16(bf16x8 a, bf16x8 b, f32x4 c) {
  return __builtin_amdgcn_mfma_f32_16x16x32_bf16(a, b, c, 0, 0, 0);
}
DEVI unsigned pk2(float lo, float hi) {
  return (unsigned)f2bfu(lo) | ((unsigned)f2bfu(hi) << 16);
}

// ---------------------------------------------------------------------------
// K1: transpose x,y [B][C][L] f32 -> xT,yT [B][L][C] bf16
// grid (L/64, C/64, 4) z = which*2 + b
__global__ __launch_bounds__(256) void transpose_xy(const float* __restrict__ x,
                                                    const float* __restrict__ y,
                                                    u16* __restrict__ xT,
                                                    u16* __restrict__ yT) {
  int z = blockIdx.z;
  int which = z >> 1, b = z & 1;
  const float* src = (which ? y : x) + (size_t)b * Cn * Ln;
  u16* dst = (which ? yT : xT) + (size_t)b * Ln * Cn;
  int l0 = blockIdx.x * 64, c0 = blockIdx.y * 64;
  __shared__ float tile[64][65];
  int t = threadIdx.x;
  #pragma unroll
  for (int i = 0; i < 16; ++i) {
    int idx = i * 256 + t;
    int r = idx >> 6, cc = idx & 63;  // r: c-row, cc: l-col
    tile[r][cc] = src[(size_t)(c0 + r) * Ln + (l0 + cc)];
  }
  __syncthreads();
  // store: pack 2 bf16 per thread -> 4B/lane coalesced
  #pragma unroll
  for (int i = 0; i < 8; ++i) {
    int idx = i * 256 + t;
    int r = idx >> 5, cc = (idx & 31) * 2;  // r: l-row, cc: c-col
    unsigned pkv = pk2(tile[cc][r], tile[cc + 1][r]);
    *(unsigned*)(&dst[(size_t)(l0 + r) * Cn + (c0 + cc)]) = pkv;
  }
}

// ---------------------------------------------------------------------------
// K2: transpose Wq/Wk/Wv [H][C][D] f32 -> WT [3][H][D][C] bf16
// grid (C/64, H, 3)
__global__ __launch_bounds__(256) void transpose_w(const float* __restrict__ Wq,
                                                   const float* __restrict__ Wk,
                                                   const float* __restrict__ Wv,
                                                   u16* __restrict__ WT) {
  int c0 = blockIdx.x * 64, h = blockIdx.y, which = blockIdx.z;
  const float* src = (which == 0 ? Wq : (which == 1 ? Wk : Wv)) + (size_t)h * Cn * Dn;
  u16* dst = WT + ((size_t)which * Hn + h) * Dn * Cn;
  __shared__ float tile[64][65];
  int t = threadIdx.x;
  #pragma unroll
  for (int i = 0; i < 16; ++i) {
    int idx = i * 256 + t;
    int r = idx >> 6, cc = idx & 63;  // r: c-row, cc: d-col
    tile[r][cc] = src[(size_t)(c0 + r) * Dn + cc];
  }
  __syncthreads();
  #pragma unroll
  for (int i = 0; i < 16; ++i) {
    int idx = i * 256 + t;
    int r = idx >> 6, cc = idx & 63;  // r: d-row, cc: c-col
    dst[(size_t)r * Cn + (c0 + cc)] = f2bfu(tile[cc][r]);
  }
}

// ---------------------------------------------------------------------------
// K3: fused QKV GEMM. O[l,n] = sum_c A[l,c]*W[n,c] + bias[n]
// A bf16 [B][L][C] (xT for Q, yT for K/V); W = WT [3][1024 rows][C].
// grid (L/128, 24, B): by -> which = by>>3, hp = by&7 (heads 2hp, 2hp+1).
// 4 waves (2x2), BM=128 BN=128 BK=64. Q/K written [B][H][L][D];
// V written TRANSPOSED [B][H][D][L] via smem bounce (kills transpose_v).
__global__ __launch_bounds__(256) void gemm_qkv3(const u16* __restrict__ xT,
                                                 const u16* __restrict__ yT,
                                                 const u16* __restrict__ WT,
                                                 const float* __restrict__ bq,
                                                 const float* __restrict__ bk,
                                                 const float* __restrict__ bv,
                                                 u16* __restrict__ Qb,
                                                 u16* __restrict__ Kb,
                                                 u16* __restrict__ Vt) {
  int mt = blockIdx.x, by = blockIdx.y, b = blockIdx.z;
  int which = by >> 3, hp = by & 7;
  const u16* A = (which == 0 ? xT : yT) + (size_t)b * Ln * Cn + (size_t)mt * 128 * Cn;
  const u16* Bw = WT + ((size_t)which * 1024 + (size_t)hp * 128) * Cn;
  __shared__ __align__(16) u16 smem[2 * 128 * 64];  // lA | lB; reused as 128x128 for V transpose
  u16* lA = smem;
  u16* lB = smem + 128 * 64;
  int t = threadIdx.x, wave = t >> 6, lane = t & 63;
  int wr = wave >> 1, wc = wave & 1;
  int ml = lane & 15, kg = lane >> 4;
  f32x4 acc[4][4] = {};
  for (int k0 = 0; k0 < Cn; k0 += 64) {
    __syncthreads();
    #pragma unroll
    for (int j = 0; j < 4; ++j) {
      int slot = j * 256 + t, row = slot >> 3, p = slot & 7, c16 = p ^ (row & 7);
      *(uint4*)(&lA[slot * 8]) = *(const uint4*)(A + (size_t)row * Cn + k0 + c16 * 8);
    }
    #pragma unroll
    for (int j = 0; j < 4; ++j) {
      int slot = j * 256 + t, row = slot >> 3, p = slot & 7, c16 = p ^ (row & 7);
      *(uint4*)(&lB[slot * 8]) = *(const uint4*)(Bw + (size_t)row * Cn + k0 + c16 * 8);
    }
    __syncthreads();
    bf16x8 af[4][2], bf[4][2];
    #pragma unroll
    for (int m = 0; m < 4; ++m) {
      int row = wr * 64 + m * 16 + ml;
      #pragma unroll
      for (int kk = 0; kk < 2; ++kk) {
        int p = (kk * 4 + kg) ^ (row & 7);
        af[m][kk] = *(const bf16x8*)(&lA[row * 64 + p * 8]);
      }
    }
    #pragma unroll
    for (int n = 0; n < 4; ++n) {
      int row = wc * 64 + n * 16 + ml;
      #pragma unroll
      for (int kk = 0; kk < 2; ++kk) {
        int p = (kk * 4 + kg) ^ (row & 7);
        bf[n][kk] = *(const bf16x8*)(&lB[row * 64 + p * 8]);
      }
    }
    #pragma unroll
    for (int m = 0; m < 4; ++m)
      #pragma unroll
      for (int n = 0; n < 4; ++n)
        #pragma unroll
        for (int kk = 0; kk < 2; ++kk)
          acc[m][n] = mfma16(af[m][kk], bf[n][kk], acc[m][n]);
  }
  int head = hp * 2 + wc;
  const float* bp = (which == 0 ? bq : (which == 1 ? bk : bv));
  if (which < 2) {
    u16* O = (which == 0 ? Qb : Kb) + (((size_t)b * Hn + head) * Ln + (size_t)mt * 128) * Dn;
    #pragma unroll
    for (int n = 0; n < 4; ++n) {
      float bvv = bp[head * 64 + n * 16 + ml];
      #pragma unroll
      for (int m = 0; m < 4; ++m)
        #pragma unroll
        for (int r = 0; r < 4; ++r) {
          int row = wr * 64 + m * 16 + kg * 4 + r;
          O[(size_t)row * Dn + n * 16 + ml] = f2bfu(acc[m][n][r] + bvv);
        }
    }
  } else {
    // V: transpose through smem (128 l x 128 n), write VT [B][H][D][L]
    __syncthreads();  // all waves done with lA/lB fragments
    #pragma unroll
    for (int n = 0; n < 4; ++n) {
      float bvv = bp[head * 64 + n * 16 + ml];
      int n_loc = wc * 64 + n * 16 + ml;
      int swz = (n_loc & 7) << 4;
      #pragma unroll
      for (int m = 0; m < 4; ++m) {
        int m_base = wr * 64 + m * 16 + kg * 4;
        uint2 pkd;
        pkd.x = pk2(acc[m][n][0] + bvv, acc[m][n][1] + bvv);
        pkd.y = pk2(acc[m][n][2] + bvv, acc[m][n][3] + bvv);
        *(uint2*)(&smem[n_loc * 128 + (m_base ^ swz)]) = pkd;
      }
    }
    __syncthreads();
    u16* Vbase = Vt + ((size_t)b * Hn + hp * 2) * Dn * Ln + (size_t)mt * 128;
    #pragma unroll
    for (int i = 0; i < 8; ++i) {
      int chunk = i * 256 + t;
      int n = chunk >> 4, cc = chunk & 15;
      uint4 vv = *(const uint4*)(&smem[n * 128 + (cc ^ ((n & 7) << 1)) * 8]);
      *(uint4*)(Vbase + (size_t)n * Ln + cc * 8) = vv;  // n = h2*64+d; row stride Ln
    }
  }
}

// ---------------------------------------------------------------------------
// K5: flash attention v3: KVBLK=128, async issue-early/write-late staging.
// Q,K bf16 [B][H][L][D]; VT bf16 [B][H][D][L]; out att f32 [B][L][H*D].
// grid (L/64, H, B), 4 waves, 16 q-rows/wave.
__global__ __launch_bounds__(256) void flash_attn(const u16* __restrict__ Qg,
                                                  const u16* __restrict__ Kg,
                                                  const u16* __restrict__ Vtg,
                                                  float* __restrict__ att) {
  int qt = blockIdx.x, h = blockIdx.y, b = blockIdx.z;
  size_t bh = (size_t)b * Hn + h;
  const u16* Qp = Qg + (bh * Ln + (size_t)qt * 64) * Dn;
  const u16* Kp = Kg + bh * Ln * Dn;
  const u16* Vp = Vtg + bh * Dn * Ln;
  int t = threadIdx.x, wave = t >> 6, lane = t & 63;
  int ml = lane & 15, kg = lane >> 4, mlx = ml & 7;
  __shared__ __align__(16) u16 Kl[128 * 64];      // [kv 128][d 64] swizzled
  __shared__ __align__(16) u16 Vl[2 * 64 * 64];   // two [d 64][kv 64] tiles
  __shared__ __align__(16) u16 Pl[4][16 * 64];    // per-wave private
  u16* Pw = Pl[wave];

  constexpr float QS = 0.125f * 1.44269504f;  // fold softmax scale + log2(e) into Q
  bf16x8 qf[2];
  #pragma unroll
  for (int kk = 0; kk < 2; ++kk) {
    bf16x8 raw = *(const bf16x8*)(Qp + (size_t)(wave * 16 + ml) * Dn + kk * 32 + kg * 8);
    #pragma unroll
    for (int j = 0; j < 8; ++j) raw[j] = (__bf16)((float)raw[j] * QS);
    qf[kk] = raw;
  }

  f32x4 ctx[4] = {};
  float psum = 0.f;
  uint4 kreg[4], vreg[4];

  // prologue: stage tile 0
  #pragma unroll
  for (int j = 0; j < 4; ++j) {
    int slot = j * 256 + t, row = slot >> 3, p = slot & 7, c16 = p ^ (row & 7);
    kreg[j] = *(const uint4*)(Kp + (size_t)row * Dn + c16 * 8);
  }
  #pragma unroll
  for (int j = 0; j < 4; ++j) {
    int slot = j * 256 + t, half = slot >> 9, s2 = slot & 511;
    int row = s2 >> 3, p = s2 & 7, c16 = p ^ (row & 7);
    vreg[j] = *(const uint4*)(Vp + (size_t)row * Ln + half * 64 + c16 * 8);
  }
  #pragma unroll
  for (int j = 0; j < 4; ++j) { int slot = j * 256 + t; *(uint4*)(&Kl[slot * 8]) = kreg[j]; }
  #pragma unroll
  for (int j = 0; j < 4; ++j) { int slot = j * 256 + t; *(uint4*)(&Vl[slot * 8]) = vreg[j]; }
  __syncthreads();

  constexpr int NT = Ln / 128;
  for (int tt = 0; tt < NT; ++tt) {
    // issue next tile's global loads early (latency hides under compute)
    if (tt + 1 < NT) {
      int kv0n = (tt + 1) * 128;
      #pragma unroll
      for (int j = 0; j < 4; ++j) {
        int slot = j * 256 + t, row = slot >> 3, p = slot & 7, c16 = p ^ (row & 7);
        kreg[j] = *(const uint4*)(Kp + (size_t)(kv0n + row) * Dn + c16 * 8);
      }
      #pragma unroll
      for (int j = 0; j < 4; ++j) {
        int slot = j * 256 + t, half = slot >> 9, s2 = slot & 511;
        int row = s2 >> 3, p = s2 & 7, c16 = p ^ (row & 7);
        vreg[j] = *(const uint4*)(Vp + (size_t)row * Ln + kv0n + half * 64 + c16 * 8);
      }
    }
    // compute both 64-kv halves from LDS
    #pragma unroll
    for (int hf = 0; hf < 2; ++hf) {
      const u16* Kh = &Kl[hf * 64 * 64];
      const u16* Vh = &Vl[hf * 64 * 64];
      // S^T = K.Q^T : lane holds q = ml, kv = nt*16 + kg*4 + r
      f32x4 s[4] = {};
      #pragma unroll
      for (int nt = 0; nt < 4; ++nt) {
        int row = nt * 16 + ml;
        #pragma unroll
        for (int kk = 0; kk < 2; ++kk) {
          int p = (kk * 4 + kg) ^ mlx;
          bf16x8 kf = *(const bf16x8*)(&Kh[row * 64 + p * 8]);
          s[nt] = mfma16(kf, qf[kk], s[nt]);
        }
      }
      // P = exp2(S); per-lane partial row-sum; pack to LDS
      #pragma unroll
      for (int nt = 0; nt < 4; ++nt) {
        f32x4 e;
        #pragma unroll
        for (int r = 0; r < 4; ++r) e[r] = __builtin_amdgcn_exp2f(s[nt][r]);
        psum += (e[0] + e[1]) + (e[2] + e[3]);
        uint2 pkd;
        pkd.x = pk2(e[0], e[1]);
        pkd.y = pk2(e[2], e[3]);
        int chunk = (nt * 2 + (kg >> 1)) ^ mlx;
        *(uint2*)(&Pw[ml * 64 + chunk * 8 + (kg & 1) * 4]) = pkd;
      }
      bf16x8 pf[2];
      #pragma unroll
      for (int kk = 0; kk < 2; ++kk) {
        int c = (kk * 4 + kg) ^ mlx;
        pf[kk] = *(const bf16x8*)(&Pw[ml * 64 + c * 8]);
      }
      #pragma unroll
      for (int nt = 0; nt < 4; ++nt) {
        int row = nt * 16 + ml;
        #pragma unroll
        for (int kk = 0; kk < 2; ++kk) {
          int p = (kk * 4 + kg) ^ mlx;
          bf16x8 vf = *(const bf16x8*)(&Vh[row * 64 + p * 8]);
          ctx[nt] = mfma16(pf[kk], vf, ctx[nt]);
        }
      }
    }
    // write-late: drain loads into LDS after all waves finished reading
    if (tt + 1 < NT) {
      __syncthreads();
      #pragma unroll
      for (int j = 0; j < 4; ++j) { int slot = j * 256 + t; *(uint4*)(&Kl[slot * 8]) = kreg[j]; }
      #pragma unroll
      for (int j = 0; j < 4; ++j) { int slot = j * 256 + t; *(uint4*)(&Vl[slot * 8]) = vreg[j]; }
      __syncthreads();
    }
  }
  // full row-sum for q=ml: combine 4 kg-lane partials
  psum += __shfl_xor(psum, 16);
  psum += __shfl_xor(psum, 32);
  float inv[4];
  #pragma unroll
  for (int r = 0; r < 4; ++r) inv[r] = 1.f / __shfl(psum, kg * 4 + r);
  #pragma unroll
  for (int nt = 0; nt < 4; ++nt)
    #pragma unroll
    for (int r = 0; r < 4; ++r) {
      size_t row = (size_t)b * Ln + qt * 64 + wave * 16 + kg * 4 + r;
      att[row * Cn + h * Dn + nt * 16 + ml] = ctx[nt][r] * inv[r];
    }
}

// ---------------------------------------------------------------------------
// K6: h = xT + att ; LayerNorm over C ; out f32 [B][L][C]. grid (B*L)
__global__ __launch_bounds__(256) void ln_kernel(const float* __restrict__ att,
                                                 const u16* __restrict__ xT,
                                                 const float* __restrict__ gamma,
                                                 const float* __restrict__ beta,
                                                 float* __restrict__ out) {
  size_t row = blockIdx.x;
  const float* ap = att + row * Cn;
  const u16* xp = xT + row * Cn;
  float* op = out + row * Cn;
  int t = threadIdx.x;
  float4 a = *(const float4*)(ap + t * 4);
  ushort4 xv = *(const ushort4*)(xp + t * 4);
  float h0 = a.x + bfu2f(xv.x), h1 = a.y + bfu2f(xv.y);
  float h2 = a.z + bfu2f(xv.z), h3 = a.w + bfu2f(xv.w);
  float s = h0 + h1 + h2 + h3;
  float ss = h0 * h0 + h1 * h1 + h2 * h2 + h3 * h3;
  #pragma unroll
  for (int off = 1; off < 64; off <<= 1) {
    s += __shfl_xor(s, off);
    ss += __shfl_xor(ss, off);
  }
  __shared__ float red[8];
  int wave = t >> 6, lane = t & 63;
  if (lane == 0) { red[wave] = s; red[wave + 4] = ss; }
  __syncthreads();
  s = red[0] + red[1] + red[2] + red[3];
  ss = red[4] + red[5] + red[6] + red[7];
  float mu = s * (1.f / 1024.f);
  float var = ss * (1.f / 1024.f) - mu * mu;
  float rinv = rsqrtf(var + 1e-5f);
  float4 g = *(const float4*)(gamma + t * 4);
  float4 be = *(const float4*)(beta + t * 4);
  float4 o;
  o.x = (h0 - mu) * rinv * g.x + be.x;
  o.y = (h1 - mu) * rinv * g.y + be.y;
  o.z = (h2 - mu) * rinv * g.z + be.z;
  o.w = (h3 - mu) * rinv * g.w + be.w;
  *(float4*)(op + t * 4) = o;
}

// ---------------------------------------------------------------------------
extern "C" void kernel_launch(void* const* d_in, const int* in_sizes, int n_in,
                              void* d_out, int out_size, void* d_ws, size_t ws_size,
                              hipStream_t stream) {
  const float* x = (const float*)d_in[0];
  const float* y = (const float*)d_in[1];
  const float* Wq = (const float*)d_in[2];
  const float* Wk = (const float*)d_in[3];
  const float* Wv = (const float*)d_in[4];
  const float* bq = (const float*)d_in[5];
  const float* bk = (const float*)d_in[6];
  const float* bv = (const float*)d_in[7];
  const float* gamma = (const float*)d_in[8];
  const float* beta = (const float*)d_in[9];
  float* out = (float*)d_out;

  char* ws = (char*)d_ws;
  u16* xT = (u16*)(ws + 0);               // 8388608 B
  u16* yT = (u16*)(ws + 8388608);         // 8388608 B
  u16* WT = (u16*)(ws + 16777216);        // 6291456 B
  u16* Qb = (u16*)(ws + 23068672);        // 8388608 B
  u16* Kb = (u16*)(ws + 31457280);        // 8388608 B
  u16* VT = (u16*)(ws + 39845888);        // 8388608 B
  float* att = (float*)(ws + 48234496);   // 16777216 B (end 65011712)

  transpose_xy<<<dim3(Ln / 64, Cn / 64, 4), dim3(256), 0, stream>>>(x, y, xT, yT);
  transpose_w<<<dim3(Cn / 64, Hn, 3), dim3(256), 0, stream>>>(Wq, Wk, Wv, WT);
  gemm_qkv3<<<dim3(Ln / 128, 24, Bn), dim3(256), 0, stream>>>(xT, yT, WT, bq, bk, bv, Qb, Kb, VT);
  flash_attn<<<dim3(Ln / 64, Hn, Bn), dim3(256), 0, stream>>>(Qb, Kb, VT, att);
  ln_kernel<<<dim3(Bn * Ln), dim3(256), 0, stream>>>(att, xT, gamma, beta, out);
}

// Round 5
// 127.114 us; speedup vs baseline: 1.6752x; 1.6752x over previous
//
#include <hip/hip_runtime.h>
#include <hip/hip_bf16.h>

#define DEVI __device__ __forceinline__

typedef unsigned short u16;
typedef __bf16 bf16x8 __attribute__((ext_vector_type(8)));
typedef float f32x4 __attribute__((ext_vector_type(4)));

constexpr int Bn = 2, Cn = 1024, Ln = 2048, Hn = 16, Dn = 64;

DEVI u16 f2bfu(float f) { return __builtin_bit_cast(u16, __float2bfloat16(f)); }
DEVI float bfu2f(u16 u) { return __bfloat162float(__builtin_bit_cast(__hip_bfloat16, u)); }
DEVI f32x4 mfma16(bf16x8 a, bf16x8 b, f32x4 c) {
  return __builtin_amdgcn_mfma_f32_16x16x32_bf16(a, b, c, 0, 0, 0);
}
DEVI unsigned pk2(float lo, float hi) {
  return (unsigned)f2bfu(lo) | ((unsigned)f2bfu(hi) << 16);
}
// async global->LDS, 16B per lane; LDS dest base must be wave-uniform,
// HW adds lane*16. Global source is per-lane (pre-swizzled upstream).
DEVI void gld16(const u16* g, u16* l) {
  __builtin_amdgcn_global_load_lds(
      (const __attribute__((address_space(1))) unsigned*)g,
      (__attribute__((address_space(3))) unsigned*)l, 16, 0, 0);
}

// ---------------------------------------------------------------------------
// K1: transpose x,y [B][C][L] f32 -> xT,yT [B][L][C] bf16
// grid (L/64, C/64, 4) z = which*2 + b
__global__ __launch_bounds__(256) void transpose_xy(const float* __restrict__ x,
                                                    const float* __restrict__ y,
                                                    u16* __restrict__ xT,
                                                    u16* __restrict__ yT) {
  int z = blockIdx.z;
  int which = z >> 1, b = z & 1;
  const float* src = (which ? y : x) + (size_t)b * Cn * Ln;
  u16* dst = (which ? yT : xT) + (size_t)b * Ln * Cn;
  int l0 = blockIdx.x * 64, c0 = blockIdx.y * 64;
  __shared__ float tile[64][65];
  int t = threadIdx.x;
  #pragma unroll
  for (int i = 0; i < 16; ++i) {
    int idx = i * 256 + t;
    int r = idx >> 6, cc = idx & 63;  // r: c-row, cc: l-col
    tile[r][cc] = src[(size_t)(c0 + r) * Ln + (l0 + cc)];
  }
  __syncthreads();
  // store: pack 2 bf16 per thread -> 4B/lane coalesced
  #pragma unroll
  for (int i = 0; i < 8; ++i) {
    int idx = i * 256 + t;
    int r = idx >> 5, cc = (idx & 31) * 2;  // r: l-row, cc: c-col
    unsigned pkv = pk2(tile[cc][r], tile[cc + 1][r]);
    *(unsigned*)(&dst[(size_t)(l0 + r) * Cn + (c0 + cc)]) = pkv;
  }
}

// ---------------------------------------------------------------------------
// K2: transpose Wq/Wk/Wv [H][C][D] f32 -> WT [3][H][D][C] bf16
// grid (C/64, H, 3)
__global__ __launch_bounds__(256) void transpose_w(const float* __restrict__ Wq,
                                                   const float* __restrict__ Wk,
                                                   const float* __restrict__ Wv,
                                                   u16* __restrict__ WT) {
  int c0 = blockIdx.x * 64, h = blockIdx.y, which = blockIdx.z;
  const float* src = (which == 0 ? Wq : (which == 1 ? Wk : Wv)) + (size_t)h * Cn * Dn;
  u16* dst = WT + ((size_t)which * Hn + h) * Dn * Cn;
  __shared__ float tile[64][65];
  int t = threadIdx.x;
  #pragma unroll
  for (int i = 0; i < 16; ++i) {
    int idx = i * 256 + t;
    int r = idx >> 6, cc = idx & 63;  // r: c-row, cc: d-col
    tile[r][cc] = src[(size_t)(c0 + r) * Dn + cc];
  }
  __syncthreads();
  #pragma unroll
  for (int i = 0; i < 16; ++i) {
    int idx = i * 256 + t;
    int r = idx >> 6, cc = idx & 63;  // r: d-row, cc: c-col
    dst[(size_t)r * Cn + (c0 + cc)] = f2bfu(tile[cc][r]);
  }
}

// ---------------------------------------------------------------------------
// K3: fused QKV GEMM. O[l,n] = sum_c A[l,c]*W[n,c] + bias[n]
// A bf16 [B][L][C] (xT for Q, yT for K/V); W = WT [3][1024 rows][C].
// grid (L/128, 24, B): by -> which = by>>3, hp = by&7 (heads 2hp, 2hp+1).
// 4 waves (2x2), BM=128 BN=128 BK=64. Staging via global_load_lds (16B).
// Q/K written [B][H][L][D]; V written TRANSPOSED [B][H][D][L] via smem bounce.
__global__ __launch_bounds__(256) void gemm_qkv3(const u16* __restrict__ xT,
                                                 const u16* __restrict__ yT,
                                                 const u16* __restrict__ WT,
                                                 const float* __restrict__ bq,
                                                 const float* __restrict__ bk,
                                                 const float* __restrict__ bv,
                                                 u16* __restrict__ Qb,
                                                 u16* __restrict__ Kb,
                                                 u16* __restrict__ Vt) {
  int mt = blockIdx.x, by = blockIdx.y, b = blockIdx.z;
  int which = by >> 3, hp = by & 7;
  const u16* A = (which == 0 ? xT : yT) + (size_t)b * Ln * Cn + (size_t)mt * 128 * Cn;
  const u16* Bw = WT + ((size_t)which * 1024 + (size_t)hp * 128) * Cn;
  __shared__ __align__(16) u16 smem[2 * 128 * 64];  // lA | lB; reused as 128x128 for V transpose
  u16* lA = smem;
  u16* lB = smem + 128 * 64;
  int t = threadIdx.x, wave = t >> 6, lane = t & 63;
  int wr = wave >> 1, wc = wave & 1;
  int ml = lane & 15, kg = lane >> 4;
  f32x4 acc[4][4] = {};
  for (int k0 = 0; k0 < Cn; k0 += 64) {
    __syncthreads();
    // stage A,B (each 128x64): 1024 16B-chunks each, 4 gload_lds calls/wave
    #pragma unroll
    for (int j = 0; j < 4; ++j) {
      int q = wave * 256 + j * 64 + lane;
      int row = q >> 3, p = q & 7, c16 = p ^ (row & 7);
      gld16(A + (size_t)row * Cn + k0 + c16 * 8, &lA[(wave * 256 + j * 64) * 8]);
    }
    #pragma unroll
    for (int j = 0; j < 4; ++j) {
      int q = wave * 256 + j * 64 + lane;
      int row = q >> 3, p = q & 7, c16 = p ^ (row & 7);
      gld16(Bw + (size_t)row * Cn + k0 + c16 * 8, &lB[(wave * 256 + j * 64) * 8]);
    }
    __syncthreads();
    bf16x8 af[4][2], bf[4][2];
    #pragma unroll
    for (int m = 0; m < 4; ++m) {
      int row = wr * 64 + m * 16 + ml;
      #pragma unroll
      for (int kk = 0; kk < 2; ++kk) {
        int p = (kk * 4 + kg) ^ (row & 7);
        af[m][kk] = *(const bf16x8*)(&lA[row * 64 + p * 8]);
      }
    }
    #pragma unroll
    for (int n = 0; n < 4; ++n) {
      int row = wc * 64 + n * 16 + ml;
      #pragma unroll
      for (int kk = 0; kk < 2; ++kk) {
        int p = (kk * 4 + kg) ^ (row & 7);
        bf[n][kk] = *(const bf16x8*)(&lB[row * 64 + p * 8]);
      }
    }
    #pragma unroll
    for (int m = 0; m < 4; ++m)
      #pragma unroll
      for (int n = 0; n < 4; ++n)
        #pragma unroll
        for (int kk = 0; kk < 2; ++kk)
          acc[m][n] = mfma16(af[m][kk], bf[n][kk], acc[m][n]);
  }
  int head = hp * 2 + wc;
  const float* bp = (which == 0 ? bq : (which == 1 ? bk : bv));
  if (which < 2) {
    u16* O = (which == 0 ? Qb : Kb) + (((size_t)b * Hn + head) * Ln + (size_t)mt * 128) * Dn;
    #pragma unroll
    for (int n = 0; n < 4; ++n) {
      float bvv = bp[head * 64 + n * 16 + ml];
      #pragma unroll
      for (int m = 0; m < 4; ++m)
        #pragma unroll
        for (int r = 0; r < 4; ++r) {
          int row = wr * 64 + m * 16 + kg * 4 + r;
          O[(size_t)row * Dn + n * 16 + ml] = f2bfu(acc[m][n][r] + bvv);
        }
    }
  } else {
    // V: transpose through smem (128 l x 128 n), write VT [B][H][D][L]
    __syncthreads();  // all waves done with lA/lB fragments
    #pragma unroll
    for (int n = 0; n < 4; ++n) {
      float bvv = bp[head * 64 + n * 16 + ml];
      int n_loc = wc * 64 + n * 16 + ml;
      int swz = (n_loc & 7) << 4;
      #pragma unroll
      for (int m = 0; m < 4; ++m) {
        int m_base = wr * 64 + m * 16 + kg * 4;
        uint2 pkd;
        pkd.x = pk2(acc[m][n][0] + bvv, acc[m][n][1] + bvv);
        pkd.y = pk2(acc[m][n][2] + bvv, acc[m][n][3] + bvv);
        *(uint2*)(&smem[n_loc * 128 + (m_base ^ swz)]) = pkd;
      }
    }
    __syncthreads();
    u16* Vbase = Vt + ((size_t)b * Hn + hp * 2) * Dn * Ln + (size_t)mt * 128;
    #pragma unroll
    for (int i = 0; i < 8; ++i) {
      int chunk = i * 256 + t;
      int n = chunk >> 4, cc = chunk & 15;
      uint4 vv = *(const uint4*)(&smem[n * 128 + (cc ^ ((n & 7) << 1)) * 8]);
      *(uint4*)(Vbase + (size_t)n * Ln + cc * 8) = vv;  // n = h2*64+d; row stride Ln
    }
  }
}

// ---------------------------------------------------------------------------
// K5: flash attention v4: KVBLK=64 double-buffered via global_load_lds,
// one barrier per tile. Q,K bf16 [B][H][L][D]; VT bf16 [B][H][D][L];
// out att f32 [B][L][H*D]. grid (L/64, H, B), 4 waves, 16 q-rows/wave.
__global__ __launch_bounds__(256) void flash_attn(const u16* __restrict__ Qg,
                                                  const u16* __restrict__ Kg,
                                                  const u16* __restrict__ Vtg,
                                                  float* __restrict__ att) {
  int qt = blockIdx.x, h = blockIdx.y, b = blockIdx.z;
  size_t bh = (size_t)b * Hn + h;
  const u16* Qp = Qg + (bh * Ln + (size_t)qt * 64) * Dn;
  const u16* Kp = Kg + bh * Ln * Dn;
  const u16* Vp = Vtg + bh * Dn * Ln;
  int t = threadIdx.x, wave = t >> 6, lane = t & 63;
  int ml = lane & 15, kg = lane >> 4, mlx = ml & 7;
  __shared__ __align__(16) u16 Kl[2][64 * 64];   // [kv 64][d 64] swizzled
  __shared__ __align__(16) u16 Vl[2][64 * 64];   // [d 64][kv 64] swizzled
  __shared__ __align__(16) u16 Pl[4][16 * 64];   // per-wave private
  u16* Pw = Pl[wave];

  constexpr float QS = 0.125f * 1.44269504f;  // softmax scale + log2(e) folded into Q
  bf16x8 qf[2];
  #pragma unroll
  for (int kk = 0; kk < 2; ++kk) {
    bf16x8 raw = *(const bf16x8*)(Qp + (size_t)(wave * 16 + ml) * Dn + kk * 32 + kg * 8);
    #pragma unroll
    for (int j = 0; j < 8; ++j) raw[j] = (__bf16)((float)raw[j] * QS);
    qf[kk] = raw;
  }

  f32x4 ctx[4] = {};
  float psum = 0.f;

  auto stage = [&](int buf, int kv0) {
    #pragma unroll
    for (int j = 0; j < 2; ++j) {
      int q = wave * 128 + j * 64 + lane;
      int row = q >> 3, p = q & 7, c16 = p ^ (row & 7);
      gld16(Kp + (size_t)(kv0 + row) * Dn + c16 * 8, &Kl[buf][(wave * 128 + j * 64) * 8]);
    }
    #pragma unroll
    for (int j = 0; j < 2; ++j) {
      int q = wave * 128 + j * 64 + lane;
      int row = q >> 3, p = q & 7, c16 = p ^ (row & 7);
      gld16(Vp + (size_t)row * Ln + kv0 + c16 * 8, &Vl[buf][(wave * 128 + j * 64) * 8]);
    }
  };

  stage(0, 0);
  __syncthreads();  // compiler drains vmcnt before s_barrier

  constexpr int NT = Ln / 64;
  for (int tt = 0; tt < NT; ++tt) {
    int cur = tt & 1;
    if (tt + 1 < NT) stage(cur ^ 1, (tt + 1) * 64);  // async, lands by next barrier
    const u16* Kh = Kl[cur];
    const u16* Vh = Vl[cur];
    // S^T = K.Q^T : lane holds q = ml, kv = nt*16 + kg*4 + r
    f32x4 s[4] = {};
    #pragma unroll
    for (int nt = 0; nt < 4; ++nt) {
      int row = nt * 16 + ml;
      #pragma unroll
      for (int kk = 0; kk < 2; ++kk) {
        int p = (kk * 4 + kg) ^ mlx;
        bf16x8 kf = *(const bf16x8*)(&Kh[row * 64 + p * 8]);
        s[nt] = mfma16(kf, qf[kk], s[nt]);
      }
    }
    // P = exp2(S); per-lane partial row-sum; pack to wave-private LDS
    #pragma unroll
    for (int nt = 0; nt < 4; ++nt) {
      f32x4 e;
      #pragma unroll
      for (int r = 0; r < 4; ++r) e[r] = __builtin_amdgcn_exp2f(s[nt][r]);
      psum += (e[0] + e[1]) + (e[2] + e[3]);
      uint2 pkd;
      pkd.x = pk2(e[0], e[1]);
      pkd.y = pk2(e[2], e[3]);
      int chunk = (nt * 2 + (kg >> 1)) ^ mlx;
      *(uint2*)(&Pw[ml * 64 + chunk * 8 + (kg & 1) * 4]) = pkd;
    }
    bf16x8 pf[2];
    #pragma unroll
    for (int kk = 0; kk < 2; ++kk) {
      int c = (kk * 4 + kg) ^ mlx;
      pf[kk] = *(const bf16x8*)(&Pw[ml * 64 + c * 8]);
    }
    // ctx += P V
    #pragma unroll
    for (int nt = 0; nt < 4; ++nt) {
      int row = nt * 16 + ml;
      #pragma unroll
      for (int kk = 0; kk < 2; ++kk) {
        int p = (kk * 4 + kg) ^ mlx;
        bf16x8 vf = *(const bf16x8*)(&Vh[row * 64 + p * 8]);
        ctx[nt] = mfma16(pf[kk], vf, ctx[nt]);
      }
    }
    if (tt + 1 < NT) __syncthreads();  // staged loads landed; all waves done with cur
  }
  // full row-sum for q=ml: combine 4 kg-lane partials
  psum += __shfl_xor(psum, 16);
  psum += __shfl_xor(psum, 32);
  float inv[4];
  #pragma unroll
  for (int r = 0; r < 4; ++r) inv[r] = 1.f / __shfl(psum, kg * 4 + r);
  #pragma unroll
  for (int nt = 0; nt < 4; ++nt)
    #pragma unroll
    for (int r = 0; r < 4; ++r) {
      size_t row = (size_t)b * Ln + qt * 64 + wave * 16 + kg * 4 + r;
      att[row * Cn + h * Dn + nt * 16 + ml] = ctx[nt][r] * inv[r];
    }
}

// ---------------------------------------------------------------------------
// K6: h = xT + att ; LayerNorm over C ; out f32 [B][L][C]. grid (B*L)
__global__ __launch_bounds__(256) void ln_kernel(const float* __restrict__ att,
                                                 const u16* __restrict__ xT,
                                                 const float* __restrict__ gamma,
                                                 const float* __restrict__ beta,
                                                 float* __restrict__ out) {
  size_t row = blockIdx.x;
  const float* ap = att + row * Cn;
  const u16* xp = xT + row * Cn;
  float* op = out + row * Cn;
  int t = threadIdx.x;
  float4 a = *(const float4*)(ap + t * 4);
  ushort4 xv = *(const ushort4*)(xp + t * 4);
  float h0 = a.x + bfu2f(xv.x), h1 = a.y + bfu2f(xv.y);
  float h2 = a.z + bfu2f(xv.z), h3 = a.w + bfu2f(xv.w);
  float s = h0 + h1 + h2 + h3;
  float ss = h0 * h0 + h1 * h1 + h2 * h2 + h3 * h3;
  #pragma unroll
  for (int off = 1; off < 64; off <<= 1) {
    s += __shfl_xor(s, off);
    ss += __shfl_xor(ss, off);
  }
  __shared__ float red[8];
  int wave = t >> 6, lane = t & 63;
  if (lane == 0) { red[wave] = s; red[wave + 4] = ss; }
  __syncthreads();
  s = red[0] + red[1] + red[2] + red[3];
  ss = red[4] + red[5] + red[6] + red[7];
  float mu = s * (1.f / 1024.f);
  float var = ss * (1.f / 1024.f) - mu * mu;
  float rinv = rsqrtf(var + 1e-5f);
  float4 g = *(const float4*)(gamma + t * 4);
  float4 be = *(const float4*)(beta + t * 4);
  float4 o;
  o.x = (h0 - mu) * rinv * g.x + be.x;
  o.y = (h1 - mu) * rinv * g.y + be.y;
  o.z = (h2 - mu) * rinv * g.z + be.z;
  o.w = (h3 - mu) * rinv * g.w + be.w;
  *(float4*)(op + t * 4) = o;
}

// ---------------------------------------------------------------------------
extern "C" void kernel_launch(void* const* d_in, const int* in_sizes, int n_in,
                              void* d_out, int out_size, void* d_ws, size_t ws_size,
                              hipStream_t stream) {
  const float* x = (const float*)d_in[0];
  const float* y = (const float*)d_in[1];
  const float* Wq = (const float*)d_in[2];
  const float* Wk = (const float*)d_in[3];
  const float* Wv = (const float*)d_in[4];
  const float* bq = (const float*)d_in[5];
  const float* bk = (const float*)d_in[6];
  const float* bv = (const float*)d_in[7];
  const float* gamma = (const float*)d_in[8];
  const float* beta = (const float*)d_in[9];
  float* out = (float*)d_out;

  char* ws = (char*)d_ws;
  u16* xT = (u16*)(ws + 0);               // 8388608 B
  u16* yT = (u16*)(ws + 8388608);         // 8388608 B
  u16* WT = (u16*)(ws + 16777216);        // 6291456 B
  u16* Qb = (u16*)(ws + 23068672);        // 8388608 B
  u16* Kb = (u16*)(ws + 31457280);        // 8388608 B
  u16* VT = (u16*)(ws + 39845888);        // 8388608 B
  float* att = (float*)(ws + 48234496);   // 16777216 B (end 65011712)

  transpose_xy<<<dim3(Ln / 64, Cn / 64, 4), dim3(256), 0, stream>>>(x, y, xT, yT);
  transpose_w<<<dim3(Cn / 64, Hn, 3), dim3(256), 0, stream>>>(Wq, Wk, Wv, WT);
  gemm_qkv3<<<dim3(Ln / 128, 24, Bn), dim3(256), 0, stream>>>(xT, yT, WT, bq, bk, bv, Qb, Kb, VT);
  flash_attn<<<dim3(Ln / 64, Hn, Bn), dim3(256), 0, stream>>>(Qb, Kb, VT, att);
  ln_kernel<<<dim3(Bn * Ln), dim3(256), 0, stream>>>(att, xT, gamma, beta, out);
}

// Round 6
// 123.006 us; speedup vs baseline: 1.7312x; 1.0334x over previous
//
#include <hip/hip_runtime.h>
#include <hip/hip_bf16.h>

#define DEVI __device__ __forceinline__

typedef unsigned short u16;
typedef __bf16 bf16x8 __attribute__((ext_vector_type(8)));
typedef float f32x4 __attribute__((ext_vector_type(4)));

constexpr int Bn = 2, Cn = 1024, Ln = 2048, Hn = 16, Dn = 64;

DEVI u16 f2bfu(float f) { return __builtin_bit_cast(u16, __float2bfloat16(f)); }
DEVI float bfu2f(u16 u) { return __bfloat162float(__builtin_bit_cast(__hip_bfloat16, u)); }
DEVI f32x4 mfma16(bf16x8 a, bf16x8 b, f32x4 c) {
  return __builtin_amdgcn_mfma_f32_16x16x32_bf16(a, b, c, 0, 0, 0);
}
DEVI unsigned pk2(float lo, float hi) {
  return (unsigned)f2bfu(lo) | ((unsigned)f2bfu(hi) << 16);
}
// async global->LDS, 16B per lane; LDS dest base must be wave-uniform,
// HW adds lane*16. Global source is per-lane (pre-swizzled upstream).
DEVI void gld16(const u16* g, u16* l) {
  __builtin_amdgcn_global_load_lds(
      (const __attribute__((address_space(1))) unsigned*)g,
      (__attribute__((address_space(3))) unsigned*)l, 16, 0, 0);
}

// ---------------------------------------------------------------------------
// K1: transpose x,y [B][C][L] f32 -> xT,yT [B][L][C] bf16
// grid (L/64, C/64, 4) z = which*2 + b
__global__ __launch_bounds__(256) void transpose_xy(const float* __restrict__ x,
                                                    const float* __restrict__ y,
                                                    u16* __restrict__ xT,
                                                    u16* __restrict__ yT) {
  int z = blockIdx.z;
  int which = z >> 1, b = z & 1;
  const float* src = (which ? y : x) + (size_t)b * Cn * Ln;
  u16* dst = (which ? yT : xT) + (size_t)b * Ln * Cn;
  int l0 = blockIdx.x * 64, c0 = blockIdx.y * 64;
  __shared__ float tile[64][65];
  int t = threadIdx.x;
  #pragma unroll
  for (int i = 0; i < 16; ++i) {
    int idx = i * 256 + t;
    int r = idx >> 6, cc = idx & 63;  // r: c-row, cc: l-col
    tile[r][cc] = src[(size_t)(c0 + r) * Ln + (l0 + cc)];
  }
  __syncthreads();
  // store: pack 2 bf16 per thread -> 4B/lane coalesced
  #pragma unroll
  for (int i = 0; i < 8; ++i) {
    int idx = i * 256 + t;
    int r = idx >> 5, cc = (idx & 31) * 2;  // r: l-row, cc: c-col
    unsigned pkv = pk2(tile[cc][r], tile[cc + 1][r]);
    *(unsigned*)(&dst[(size_t)(l0 + r) * Cn + (c0 + cc)]) = pkv;
  }
}

// ---------------------------------------------------------------------------
// K2: transpose Wq/Wk/Wv [H][C][D] f32 -> WT [3][H][D][C] bf16
// grid (C/64, H, 3)
__global__ __launch_bounds__(256) void transpose_w(const float* __restrict__ Wq,
                                                   const float* __restrict__ Wk,
                                                   const float* __restrict__ Wv,
                                                   u16* __restrict__ WT) {
  int c0 = blockIdx.x * 64, h = blockIdx.y, which = blockIdx.z;
  const float* src = (which == 0 ? Wq : (which == 1 ? Wk : Wv)) + (size_t)h * Cn * Dn;
  u16* dst = WT + ((size_t)which * Hn + h) * Dn * Cn;
  __shared__ float tile[64][65];
  int t = threadIdx.x;
  #pragma unroll
  for (int i = 0; i < 16; ++i) {
    int idx = i * 256 + t;
    int r = idx >> 6, cc = idx & 63;  // r: c-row, cc: d-col
    tile[r][cc] = src[(size_t)(c0 + r) * Dn + cc];
  }
  __syncthreads();
  #pragma unroll
  for (int i = 0; i < 16; ++i) {
    int idx = i * 256 + t;
    int r = idx >> 6, cc = idx & 63;  // r: d-row, cc: c-col
    dst[(size_t)r * Cn + (c0 + cc)] = f2bfu(tile[cc][r]);
  }
}

// ---------------------------------------------------------------------------
// K3: fused QKV GEMM. O[l,n] = sum_c A[l,c]*W[n,c] + bias[n]
// A bf16 [B][L][C] (xT for Q, yT for K/V); W = WT [3][1024 rows][C].
// grid (L/128, 24, B): by -> which = by>>3, hp = by&7 (heads 2hp, 2hp+1).
// 4 waves (2x2), BM=128 BN=128 BK=64. Staging via global_load_lds (16B).
// Q/K written [B][H][L][D]; V written TRANSPOSED [B][H][D][L] via smem bounce.
__global__ __launch_bounds__(256) void gemm_qkv3(const u16* __restrict__ xT,
                                                 const u16* __restrict__ yT,
                                                 const u16* __restrict__ WT,
                                                 const float* __restrict__ bq,
                                                 const float* __restrict__ bk,
                                                 const float* __restrict__ bv,
                                                 u16* __restrict__ Qb,
                                                 u16* __restrict__ Kb,
                                                 u16* __restrict__ Vt) {
  int mt = blockIdx.x, by = blockIdx.y, b = blockIdx.z;
  int which = by >> 3, hp = by & 7;
  const u16* A = (which == 0 ? xT : yT) + (size_t)b * Ln * Cn + (size_t)mt * 128 * Cn;
  const u16* Bw = WT + ((size_t)which * 1024 + (size_t)hp * 128) * Cn;
  __shared__ __align__(16) u16 smem[2 * 128 * 64];  // lA | lB; reused as 128x128 for V transpose
  u16* lA = smem;
  u16* lB = smem + 128 * 64;
  int t = threadIdx.x, wave = t >> 6, lane = t & 63;
  int wr = wave >> 1, wc = wave & 1;
  int ml = lane & 15, kg = lane >> 4;
  f32x4 acc[4][4] = {};
  for (int k0 = 0; k0 < Cn; k0 += 64) {
    __syncthreads();
    // stage A,B (each 128x64): 1024 16B-chunks each, 4 gload_lds calls/wave
    #pragma unroll
    for (int j = 0; j < 4; ++j) {
      int q = wave * 256 + j * 64 + lane;
      int row = q >> 3, p = q & 7, c16 = p ^ (row & 7);
      gld16(A + (size_t)row * Cn + k0 + c16 * 8, &lA[(wave * 256 + j * 64) * 8]);
    }
    #pragma unroll
    for (int j = 0; j < 4; ++j) {
      int q = wave * 256 + j * 64 + lane;
      int row = q >> 3, p = q & 7, c16 = p ^ (row & 7);
      gld16(Bw + (size_t)row * Cn + k0 + c16 * 8, &lB[(wave * 256 + j * 64) * 8]);
    }
    __syncthreads();
    bf16x8 af[4][2], bf[4][2];
    #pragma unroll
    for (int m = 0; m < 4; ++m) {
      int row = wr * 64 + m * 16 + ml;
      #pragma unroll
      for (int kk = 0; kk < 2; ++kk) {
        int p = (kk * 4 + kg) ^ (row & 7);
        af[m][kk] = *(const bf16x8*)(&lA[row * 64 + p * 8]);
      }
    }
    #pragma unroll
    for (int n = 0; n < 4; ++n) {
      int row = wc * 64 + n * 16 + ml;
      #pragma unroll
      for (int kk = 0; kk < 2; ++kk) {
        int p = (kk * 4 + kg) ^ (row & 7);
        bf[n][kk] = *(const bf16x8*)(&lB[row * 64 + p * 8]);
      }
    }
    #pragma unroll
    for (int m = 0; m < 4; ++m)
      #pragma unroll
      for (int n = 0; n < 4; ++n)
        #pragma unroll
        for (int kk = 0; kk < 2; ++kk)
          acc[m][n] = mfma16(af[m][kk], bf[n][kk], acc[m][n]);
  }
  int head = hp * 2 + wc;
  const float* bp = (which == 0 ? bq : (which == 1 ? bk : bv));
  if (which < 2) {
    u16* O = (which == 0 ? Qb : Kb) + (((size_t)b * Hn + head) * Ln + (size_t)mt * 128) * Dn;
    #pragma unroll
    for (int n = 0; n < 4; ++n) {
      float bvv = bp[head * 64 + n * 16 + ml];
      #pragma unroll
      for (int m = 0; m < 4; ++m)
        #pragma unroll
        for (int r = 0; r < 4; ++r) {
          int row = wr * 64 + m * 16 + kg * 4 + r;
          O[(size_t)row * Dn + n * 16 + ml] = f2bfu(acc[m][n][r] + bvv);
        }
    }
  } else {
    // V: transpose through smem (128 l x 128 n), write VT [B][H][D][L]
    __syncthreads();  // all waves done with lA/lB fragments
    #pragma unroll
    for (int n = 0; n < 4; ++n) {
      float bvv = bp[head * 64 + n * 16 + ml];
      int n_loc = wc * 64 + n * 16 + ml;
      int swz = (n_loc & 7) << 4;
      #pragma unroll
      for (int m = 0; m < 4; ++m) {
        int m_base = wr * 64 + m * 16 + kg * 4;
        uint2 pkd;
        pkd.x = pk2(acc[m][n][0] + bvv, acc[m][n][1] + bvv);
        pkd.y = pk2(acc[m][n][2] + bvv, acc[m][n][3] + bvv);
        *(uint2*)(&smem[n_loc * 128 + (m_base ^ swz)]) = pkd;
      }
    }
    __syncthreads();
    u16* Vbase = Vt + ((size_t)b * Hn + hp * 2) * Dn * Ln + (size_t)mt * 128;
    #pragma unroll
    for (int i = 0; i < 8; ++i) {
      int chunk = i * 256 + t;
      int n = chunk >> 4, cc = chunk & 15;
      uint4 vv = *(const uint4*)(&smem[n * 128 + (cc ^ ((n & 7) << 1)) * 8]);
      *(uint4*)(Vbase + (size_t)n * Ln + cc * 8) = vv;  // n = h2*64+d; row stride Ln
    }
  }
}

// ---------------------------------------------------------------------------
// K5: flash attention v5: 8 waves (512 thr), wave-pairs split each 64-kv tile
// in half (wave g = w>>2 does kv [g*32,g*32+32)). K/V double-buffered via
// global_load_lds, one barrier/tile. Partial ctx/psum combined through dead
// K/V LDS at the end. Q,K bf16 [B][H][L][D]; VT bf16 [B][H][D][L];
// out att bf16 [B][L][H*D]. grid (L/64, H, B).
__global__ __launch_bounds__(512, 8) void flash_attn(const u16* __restrict__ Qg,
                                                     const u16* __restrict__ Kg,
                                                     const u16* __restrict__ Vtg,
                                                     u16* __restrict__ att) {
  int qt = blockIdx.x, h = blockIdx.y, b = blockIdx.z;
  size_t bh = (size_t)b * Hn + h;
  const u16* Qp = Qg + (bh * Ln + (size_t)qt * 64) * Dn;
  const u16* Kp = Kg + bh * Ln * Dn;
  const u16* Vp = Vtg + bh * Dn * Ln;
  int t = threadIdx.x, wave = t >> 6, lane = t & 63;
  int qs = wave & 3, g = wave >> 2;       // q-slice, kv-half
  int ml = lane & 15, kg = lane >> 4;
  __shared__ __align__(16) u16 Kl[2][64 * 64];   // [kv 64][d 64] swizzled
  __shared__ __align__(16) u16 Vl[2][64 * 64];   // [d 64][kv 64] swizzled
  __shared__ __align__(16) u16 Pl[8][16 * 32];   // per-wave [q16][kv32]
  u16* Pw = Pl[wave];

  constexpr float QS = 0.125f * 1.44269504f;  // softmax scale + log2(e) folded into Q
  bf16x8 qf[2];
  #pragma unroll
  for (int kk = 0; kk < 2; ++kk) {
    bf16x8 raw = *(const bf16x8*)(Qp + (size_t)(qs * 16 + ml) * Dn + kk * 32 + kg * 8);
    #pragma unroll
    for (int j = 0; j < 8; ++j) raw[j] = (__bf16)((float)raw[j] * QS);
    qf[kk] = raw;
  }

  f32x4 ctx[4] = {};
  float psum = 0.f;

  // 512 threads stage one 16B chunk each per buffer (64x64 u16 = 512 chunks)
  auto stage = [&](int buf, int kv0) {
    int rowk = t >> 3, p = t & 7, c16 = p ^ (rowk & 7);
    gld16(Kp + (size_t)(kv0 + rowk) * Dn + c16 * 8, &Kl[buf][wave * 512]);
    gld16(Vp + (size_t)rowk * Ln + kv0 + c16 * 8, &Vl[buf][wave * 512]);
  };

  stage(0, 0);
  __syncthreads();  // compiler drains vmcnt before s_barrier

  constexpr int NT = Ln / 64;
  for (int tt = 0; tt < NT; ++tt) {
    int cur = tt & 1;
    if (tt + 1 < NT) stage(cur ^ 1, (tt + 1) * 64);  // async, lands by next barrier
    const u16* Kh = Kl[cur];
    const u16* Vh = Vl[cur];
    // S^T = K.Q^T on this wave's kv half: lane holds q=ml, kv=g*32+nt*16+kg*4+r
    f32x4 s[2] = {};
    #pragma unroll
    for (int nt = 0; nt < 2; ++nt) {
      int row = g * 32 + nt * 16 + ml;
      #pragma unroll
      for (int kk = 0; kk < 2; ++kk) {
        int p = (kk * 4 + kg) ^ (row & 7);
        bf16x8 kf = *(const bf16x8*)(&Kh[row * 64 + p * 8]);
        s[nt] = mfma16(kf, qf[kk], s[nt]);
      }
    }
    // P = exp2(S); per-lane partial row-sum; pack to wave-private LDS
    // Pl row q=ml (32 u16), 16B chunks XOR-swizzled by (ml&3)
    #pragma unroll
    for (int nt = 0; nt < 2; ++nt) {
      f32x4 e;
      #pragma unroll
      for (int r = 0; r < 4; ++r) e[r] = __builtin_amdgcn_exp2f(s[nt][r]);
      psum += (e[0] + e[1]) + (e[2] + e[3]);
      uint2 pkd;
      pkd.x = pk2(e[0], e[1]);
      pkd.y = pk2(e[2], e[3]);
      int chunk = (nt * 2 + (kg >> 1)) ^ (ml & 3);
      *(uint2*)(&Pw[ml * 32 + chunk * 8 + (kg & 1) * 4]) = pkd;
    }
    // A-frag for PV: P[q=ml][kv = kg*8 + j] (K=32 over this half)
    bf16x8 pf = *(const bf16x8*)(&Pw[ml * 32 + (kg ^ (ml & 3)) * 8]);
    // ctx += P V over this kv half
    #pragma unroll
    for (int nt = 0; nt < 4; ++nt) {
      int row = nt * 16 + ml;
      int p = (g * 4 + kg) ^ (row & 7);
      bf16x8 vf = *(const bf16x8*)(&Vh[row * 64 + p * 8]);
      ctx[nt] = mfma16(pf, vf, ctx[nt]);
    }
    if (tt + 1 < NT) __syncthreads();  // staged loads landed; all waves done with cur
  }
  // combine wave-pair partials (g=1 -> g=0) through dead K/V LDS
  __syncthreads();
  float* comb = (float*)&Kl[0][0];   // [4 qs][16][64 lanes] f32 = 16KB
  float* psA = (float*)&Vl[0][0];    // [4 qs][64 lanes]
  if (g == 1) {
    int base = qs * 1024 + lane;
    #pragma unroll
    for (int nt = 0; nt < 4; ++nt)
      #pragma unroll
      for (int r = 0; r < 4; ++r)
        comb[base + (nt * 4 + r) * 64] = ctx[nt][r];
    psA[qs * 64 + lane] = psum;
  }
  __syncthreads();
  if (g == 0) {
    int base = qs * 1024 + lane;
    #pragma unroll
    for (int nt = 0; nt < 4; ++nt)
      #pragma unroll
      for (int r = 0; r < 4; ++r)
        ctx[nt][r] += comb[base + (nt * 4 + r) * 64];
    psum += psA[qs * 64 + lane];
    psum += __shfl_xor(psum, 16);
    psum += __shfl_xor(psum, 32);
    float inv[4];
    #pragma unroll
    for (int r = 0; r < 4; ++r) inv[r] = 1.f / __shfl(psum, kg * 4 + r);
    #pragma unroll
    for (int nt = 0; nt < 4; ++nt)
      #pragma unroll
      for (int r = 0; r < 4; ++r) {
        size_t row = (size_t)b * Ln + qt * 64 + qs * 16 + kg * 4 + r;
        att[row * Cn + h * Dn + nt * 16 + ml] = f2bfu(ctx[nt][r] * inv[r]);
      }
  }
}

// ---------------------------------------------------------------------------
// K6: h = xT + att ; LayerNorm over C ; out f32 [B][L][C]. grid (B*L)
__global__ __launch_bounds__(256) void ln_kernel(const u16* __restrict__ att,
                                                 const u16* __restrict__ xT,
                                                 const float* __restrict__ gamma,
                                                 const float* __restrict__ beta,
                                                 float* __restrict__ out) {
  size_t row = blockIdx.x;
  const u16* ap = att + row * Cn;
  const u16* xp = xT + row * Cn;
  float* op = out + row * Cn;
  int t = threadIdx.x;
  ushort4 a4 = *(const ushort4*)(ap + t * 4);
  ushort4 xv = *(const ushort4*)(xp + t * 4);
  float h0 = bfu2f(a4.x) + bfu2f(xv.x), h1 = bfu2f(a4.y) + bfu2f(xv.y);
  float h2 = bfu2f(a4.z) + bfu2f(xv.z), h3 = bfu2f(a4.w) + bfu2f(xv.w);
  float s = h0 + h1 + h2 + h3;
  float ss = h0 * h0 + h1 * h1 + h2 * h2 + h3 * h3;
  #pragma unroll
  for (int off = 1; off < 64; off <<= 1) {
    s += __shfl_xor(s, off);
    ss += __shfl_xor(ss, off);
  }
  __shared__ float red[8];
  int wave = t >> 6, lane = t & 63;
  if (lane == 0) { red[wave] = s; red[wave + 4] = ss; }
  __syncthreads();
  s = red[0] + red[1] + red[2] + red[3];
  ss = red[4] + red[5] + red[6] + red[7];
  float mu = s * (1.f / 1024.f);
  float var = ss * (1.f / 1024.f) - mu * mu;
  float rinv = rsqrtf(var + 1e-5f);
  float4 gmv = *(const float4*)(gamma + t * 4);
  float4 bev = *(const float4*)(beta + t * 4);
  float4 o;
  o.x = (h0 - mu) * rinv * gmv.x + bev.x;
  o.y = (h1 - mu) * rinv * gmv.y + bev.y;
  o.z = (h2 - mu) * rinv * gmv.z + bev.z;
  o.w = (h3 - mu) * rinv * gmv.w + bev.w;
  *(float4*)(op + t * 4) = o;
}

// ---------------------------------------------------------------------------
extern "C" void kernel_launch(void* const* d_in, const int* in_sizes, int n_in,
                              void* d_out, int out_size, void* d_ws, size_t ws_size,
                              hipStream_t stream) {
  const float* x = (const float*)d_in[0];
  const float* y = (const float*)d_in[1];
  const float* Wq = (const float*)d_in[2];
  const float* Wk = (const float*)d_in[3];
  const float* Wv = (const float*)d_in[4];
  const float* bq = (const float*)d_in[5];
  const float* bk = (const float*)d_in[6];
  const float* bv = (const float*)d_in[7];
  const float* gamma = (const float*)d_in[8];
  const float* beta = (const float*)d_in[9];
  float* out = (float*)d_out;

  char* ws = (char*)d_ws;
  u16* xT = (u16*)(ws + 0);               // 8388608 B
  u16* yT = (u16*)(ws + 8388608);         // 8388608 B
  u16* WT = (u16*)(ws + 16777216);        // 6291456 B
  u16* Qb = (u16*)(ws + 23068672);        // 8388608 B
  u16* Kb = (u16*)(ws + 31457280);        // 8388608 B
  u16* VT = (u16*)(ws + 39845888);        // 8388608 B
  u16* att = (u16*)(ws + 48234496);       // 8388608 B (end 56623104)

  transpose_xy<<<dim3(Ln / 64, Cn / 64, 4), dim3(256), 0, stream>>>(x, y, xT, yT);
  transpose_w<<<dim3(Cn / 64, Hn, 3), dim3(256), 0, stream>>>(Wq, Wk, Wv, WT);
  gemm_qkv3<<<dim3(Ln / 128, 24, Bn), dim3(256), 0, stream>>>(xT, yT, WT, bq, bk, bv, Qb, Kb, VT);
  flash_attn<<<dim3(Ln / 64, Hn, Bn), dim3(512), 0, stream>>>(Qb, Kb, VT, att);
  ln_kernel<<<dim3(Bn * Ln), dim3(256), 0, stream>>>(att, xT, gamma, beta, out);
}

// Round 7
// 109.805 us; speedup vs baseline: 1.9393x; 1.1202x over previous
//
#include <hip/hip_runtime.h>
#include <hip/hip_bf16.h>

#define DEVI __device__ __forceinline__

typedef unsigned short u16;
typedef __bf16 bf16x8 __attribute__((ext_vector_type(8)));
typedef float f32x4 __attribute__((ext_vector_type(4)));

constexpr int Bn = 2, Cn = 1024, Ln = 2048, Hn = 16, Dn = 64;

DEVI u16 f2bfu(float f) { return __builtin_bit_cast(u16, __float2bfloat16(f)); }
DEVI float bfu2f(u16 u) { return __bfloat162float(__builtin_bit_cast(__hip_bfloat16, u)); }
DEVI f32x4 mfma16(bf16x8 a, bf16x8 b, f32x4 c) {
  return __builtin_amdgcn_mfma_f32_16x16x32_bf16(a, b, c, 0, 0, 0);
}
DEVI unsigned pk2(float lo, float hi) {
  return (unsigned)f2bfu(lo) | ((unsigned)f2bfu(hi) << 16);
}
// async global->LDS, 16B per lane; LDS dest base must be wave-uniform,
// HW adds lane*16. Global source is per-lane (pre-swizzled upstream).
DEVI void gld16(const u16* g, u16* l) {
  __builtin_amdgcn_global_load_lds(
      (const __attribute__((address_space(1))) unsigned*)g,
      (__attribute__((address_space(3))) unsigned*)l, 16, 0, 0);
}
// LDS bank swizzle: fold row bit3 into bank-bit2 so permuted-row reads
// (which fix row&7 to 4 values) still spread over 8 bank-groups.
DEVI int fsw(int row) { return (row & 7) ^ (((row >> 3) & 1) << 2); }

// ---------------------------------------------------------------------------
// K1: transpose x,y [B][C][L] f32 -> xT,yT [B][L][C] bf16
// grid (L/64, C/64, 4) z = which*2 + b
__global__ __launch_bounds__(256) void transpose_xy(const float* __restrict__ x,
                                                    const float* __restrict__ y,
                                                    u16* __restrict__ xT,
                                                    u16* __restrict__ yT) {
  int z = blockIdx.z;
  int which = z >> 1, b = z & 1;
  const float* src = (which ? y : x) + (size_t)b * Cn * Ln;
  u16* dst = (which ? yT : xT) + (size_t)b * Ln * Cn;
  int l0 = blockIdx.x * 64, c0 = blockIdx.y * 64;
  __shared__ float tile[64][65];
  int t = threadIdx.x;
  #pragma unroll
  for (int i = 0; i < 16; ++i) {
    int idx = i * 256 + t;
    int r = idx >> 6, cc = idx & 63;  // r: c-row, cc: l-col
    tile[r][cc] = src[(size_t)(c0 + r) * Ln + (l0 + cc)];
  }
  __syncthreads();
  // store: pack 2 bf16 per thread -> 4B/lane coalesced
  #pragma unroll
  for (int i = 0; i < 8; ++i) {
    int idx = i * 256 + t;
    int r = idx >> 5, cc = (idx & 31) * 2;  // r: l-row, cc: c-col
    unsigned pkv = pk2(tile[cc][r], tile[cc + 1][r]);
    *(unsigned*)(&dst[(size_t)(l0 + r) * Cn + (c0 + cc)]) = pkv;
  }
}

// ---------------------------------------------------------------------------
// K2: transpose Wq/Wk/Wv [H][C][D] f32 -> WT [3][H][D][C] bf16
// grid (C/64, H, 3)
__global__ __launch_bounds__(256) void transpose_w(const float* __restrict__ Wq,
                                                   const float* __restrict__ Wk,
                                                   const float* __restrict__ Wv,
                                                   u16* __restrict__ WT) {
  int c0 = blockIdx.x * 64, h = blockIdx.y, which = blockIdx.z;
  const float* src = (which == 0 ? Wq : (which == 1 ? Wk : Wv)) + (size_t)h * Cn * Dn;
  u16* dst = WT + ((size_t)which * Hn + h) * Dn * Cn;
  __shared__ float tile[64][65];
  int t = threadIdx.x;
  #pragma unroll
  for (int i = 0; i < 16; ++i) {
    int idx = i * 256 + t;
    int r = idx >> 6, cc = idx & 63;  // r: c-row, cc: d-col
    tile[r][cc] = src[(size_t)(c0 + r) * Dn + cc];
  }
  __syncthreads();
  #pragma unroll
  for (int i = 0; i < 16; ++i) {
    int idx = i * 256 + t;
    int r = idx >> 6, cc = idx & 63;  // r: d-row, cc: c-col
    dst[(size_t)r * Cn + (c0 + cc)] = f2bfu(tile[cc][r]);
  }
}

// ---------------------------------------------------------------------------
// K3: fused QKV GEMM. O[l,n] = sum_c A[l,c]*W[n,c] + bias[n]
// A bf16 [B][L][C] (xT for Q, yT for K/V); W = WT [3][1024 rows][C].
// grid (L/128, 24, B): by -> which = by>>3, hp = by&7 (heads 2hp, 2hp+1).
// 4 waves (2x2), BM=128 BN=128 BK=64. Staging via global_load_lds (16B).
// Q/K written [B][H][L][D]; V written TRANSPOSED [B][H][D][L] via smem bounce.
__global__ __launch_bounds__(256) void gemm_qkv3(const u16* __restrict__ xT,
                                                 const u16* __restrict__ yT,
                                                 const u16* __restrict__ WT,
                                                 const float* __restrict__ bq,
                                                 const float* __restrict__ bk,
                                                 const float* __restrict__ bv,
                                                 u16* __restrict__ Qb,
                                                 u16* __restrict__ Kb,
                                                 u16* __restrict__ Vt) {
  int mt = blockIdx.x, by = blockIdx.y, b = blockIdx.z;
  int which = by >> 3, hp = by & 7;
  const u16* A = (which == 0 ? xT : yT) + (size_t)b * Ln * Cn + (size_t)mt * 128 * Cn;
  const u16* Bw = WT + ((size_t)which * 1024 + (size_t)hp * 128) * Cn;
  __shared__ __align__(16) u16 smem[2 * 128 * 64];  // lA | lB; reused as 128x128 for V transpose
  u16* lA = smem;
  u16* lB = smem + 128 * 64;
  int t = threadIdx.x, wave = t >> 6, lane = t & 63;
  int wr = wave >> 1, wc = wave & 1;
  int ml = lane & 15, kg = lane >> 4;
  f32x4 acc[4][4] = {};
  for (int k0 = 0; k0 < Cn; k0 += 64) {
    __syncthreads();
    // stage A,B (each 128x64): 1024 16B-chunks each, 4 gload_lds calls/wave
    #pragma unroll
    for (int j = 0; j < 4; ++j) {
      int q = wave * 256 + j * 64 + lane;
      int row = q >> 3, p = q & 7, c16 = p ^ (row & 7);
      gld16(A + (size_t)row * Cn + k0 + c16 * 8, &lA[(wave * 256 + j * 64) * 8]);
    }
    #pragma unroll
    for (int j = 0; j < 4; ++j) {
      int q = wave * 256 + j * 64 + lane;
      int row = q >> 3, p = q & 7, c16 = p ^ (row & 7);
      gld16(Bw + (size_t)row * Cn + k0 + c16 * 8, &lB[(wave * 256 + j * 64) * 8]);
    }
    __syncthreads();
    bf16x8 af[4][2], bf[4][2];
    #pragma unroll
    for (int m = 0; m < 4; ++m) {
      int row = wr * 64 + m * 16 + ml;
      #pragma unroll
      for (int kk = 0; kk < 2; ++kk) {
        int p = (kk * 4 + kg) ^ (row & 7);
        af[m][kk] = *(const bf16x8*)(&lA[row * 64 + p * 8]);
      }
    }
    #pragma unroll
    for (int n = 0; n < 4; ++n) {
      int row = wc * 64 + n * 16 + ml;
      #pragma unroll
      for (int kk = 0; kk < 2; ++kk) {
        int p = (kk * 4 + kg) ^ (row & 7);
        bf[n][kk] = *(const bf16x8*)(&lB[row * 64 + p * 8]);
      }
    }
    __builtin_amdgcn_s_setprio(1);
    #pragma unroll
    for (int m = 0; m < 4; ++m)
      #pragma unroll
      for (int n = 0; n < 4; ++n)
        #pragma unroll
        for (int kk = 0; kk < 2; ++kk)
          acc[m][n] = mfma16(af[m][kk], bf[n][kk], acc[m][n]);
    __builtin_amdgcn_s_setprio(0);
  }
  int head = hp * 2 + wc;
  const float* bp = (which == 0 ? bq : (which == 1 ? bk : bv));
  if (which < 2) {
    u16* O = (which == 0 ? Qb : Kb) + (((size_t)b * Hn + head) * Ln + (size_t)mt * 128) * Dn;
    #pragma unroll
    for (int n = 0; n < 4; ++n) {
      float bvv = bp[head * 64 + n * 16 + ml];
      #pragma unroll
      for (int m = 0; m < 4; ++m)
        #pragma unroll
        for (int r = 0; r < 4; ++r) {
          int row = wr * 64 + m * 16 + kg * 4 + r;
          O[(size_t)row * Dn + n * 16 + ml] = f2bfu(acc[m][n][r] + bvv);
        }
    }
  } else {
    // V: transpose through smem (128 l x 128 n), write VT [B][H][D][L]
    __syncthreads();  // all waves done with lA/lB fragments
    #pragma unroll
    for (int n = 0; n < 4; ++n) {
      float bvv = bp[head * 64 + n * 16 + ml];
      int n_loc = wc * 64 + n * 16 + ml;
      int swz = (n_loc & 7) << 4;
      #pragma unroll
      for (int m = 0; m < 4; ++m) {
        int m_base = wr * 64 + m * 16 + kg * 4;
        uint2 pkd;
        pkd.x = pk2(acc[m][n][0] + bvv, acc[m][n][1] + bvv);
        pkd.y = pk2(acc[m][n][2] + bvv, acc[m][n][3] + bvv);
        *(uint2*)(&smem[n_loc * 128 + (m_base ^ swz)]) = pkd;
      }
    }
    __syncthreads();
    u16* Vbase = Vt + ((size_t)b * Hn + hp * 2) * Dn * Ln + (size_t)mt * 128;
    #pragma unroll
    for (int i = 0; i < 8; ++i) {
      int chunk = i * 256 + t;
      int n = chunk >> 4, cc = chunk & 15;
      uint4 vv = *(const uint4*)(&smem[n * 128 + (cc ^ ((n & 7) << 1)) * 8]);
      *(uint4*)(Vbase + (size_t)n * Ln + cc * 8) = vv;  // n = h2*64+d; row stride Ln
    }
  }
}

// ---------------------------------------------------------------------------
// K5: flash attention v6: kv-permuted QK output => P stays in registers
// (no P LDS, no cross-lane). 8 waves, wave (qs,g): q-slice qs*16, kv-half g.
// K rows are loaded into MFMA A-rows permuted as kv(nt,rho)=8*(rho>>2)+4nt+(rho&3)
// so output lane (ml,kg) holds kv kg*8..kg*8+7 == PV A-fragment layout.
// LDS swizzle fsw spreads the permuted row set across 8 bank groups.
// XCD remap: all 32 q-blocks of one (b,h) -> same XCD (KV L2-resident).
// grid (L/64, H, B) remapped in-kernel. out att bf16 [B][L][H*D].
__global__ __launch_bounds__(512, 8) void flash_attn(const u16* __restrict__ Qg,
                                                     const u16* __restrict__ Kg,
                                                     const u16* __restrict__ Vtg,
                                                     u16* __restrict__ att) {
  // --- XCD-aware remap (8 XCDs, 1024 blocks, HW assigns n%8) ---
  int n = blockIdx.x + 32 * (blockIdx.y + 16 * blockIdx.z);
  int xcd = n & 7, m = n >> 3;
  int grp = xcd * 4 + (m >> 5);       // 0..31 -> (b,h)
  int qt = m & 31;
  int h = grp & 15, b = grp >> 4;

  size_t bh = (size_t)b * Hn + h;
  const u16* Qp = Qg + (bh * Ln + (size_t)qt * 64) * Dn;
  const u16* Kp = Kg + bh * Ln * Dn;
  const u16* Vp = Vtg + bh * Dn * Ln;
  int t = threadIdx.x, wave = t >> 6, lane = t & 63;
  int qs = wave & 3, g = wave >> 2;       // q-slice, kv-half
  int ml = lane & 15, kg = lane >> 4;
  __shared__ __align__(16) u16 Kl[2][64 * 64];   // [kv 64][d 64] fsw-swizzled
  __shared__ __align__(16) u16 Vl[2][64 * 64];   // [d 64][kv 64] fsw-swizzled

  constexpr float QS = 0.125f * 1.44269504f;  // softmax scale + log2(e) folded into Q
  bf16x8 qf[2];
  #pragma unroll
  for (int kk = 0; kk < 2; ++kk) {
    bf16x8 raw = *(const bf16x8*)(Qp + (size_t)(qs * 16 + ml) * Dn + kk * 32 + kg * 8);
    #pragma unroll
    for (int j = 0; j < 8; ++j) raw[j] = (__bf16)((float)raw[j] * QS);
    qf[kk] = raw;
  }

  f32x4 ctx[4] = {};
  float psum = 0.f;

  // 512 threads stage one 16B chunk each per buffer (64x64 u16 = 512 chunks)
  auto stage = [&](int buf, int kv0) {
    int rowk = t >> 3, p = t & 7, c16 = p ^ fsw(rowk);
    gld16(Kp + (size_t)(kv0 + rowk) * Dn + c16 * 8, &Kl[buf][wave * 512]);
    gld16(Vp + (size_t)rowk * Ln + kv0 + c16 * 8, &Vl[buf][wave * 512]);
  };

  stage(0, 0);
  __syncthreads();  // compiler drains vmcnt before s_barrier

  constexpr int NT = Ln / 64;
  for (int tt = 0; tt < NT; ++tt) {
    int cur = tt & 1;
    if (tt + 1 < NT) stage(cur ^ 1, (tt + 1) * 64);  // async, lands by next barrier
    const u16* Kh = Kl[cur];
    const u16* Vh = Vl[cur];
    // S^T = K.Q^T, kv-permuted A-rows: lane (ml,kg) reg r of subtile nt holds
    // kv = g*32 + kg*8 + nt*4 + r  (contiguous 8 kv per lane across nt!)
    f32x4 s[2] = {};
    __builtin_amdgcn_s_setprio(1);
    #pragma unroll
    for (int nt = 0; nt < 2; ++nt) {
      int rowk = g * 32 + 8 * (ml >> 2) + 4 * nt + (ml & 3);
      #pragma unroll
      for (int kk = 0; kk < 2; ++kk) {
        int p = (kk * 4 + kg) ^ fsw(rowk);
        bf16x8 kf = *(const bf16x8*)(&Kh[rowk * 64 + p * 8]);
        s[nt] = mfma16(kf, qf[kk], s[nt]);
      }
    }
    __builtin_amdgcn_s_setprio(0);
    // P = exp2(S), packed straight into the PV A-fragment (registers only)
    f32x4 e0, e1;
    #pragma unroll
    for (int r = 0; r < 4; ++r) e0[r] = __builtin_amdgcn_exp2f(s[0][r]);
    #pragma unroll
    for (int r = 0; r < 4; ++r) e1[r] = __builtin_amdgcn_exp2f(s[1][r]);
    psum += (e0[0] + e0[1]) + (e0[2] + e0[3]) + (e1[0] + e1[1]) + (e1[2] + e1[3]);
    uint4 pw;
    pw.x = pk2(e0[0], e0[1]);
    pw.y = pk2(e0[2], e0[3]);
    pw.z = pk2(e1[0], e1[1]);
    pw.w = pk2(e1[2], e1[3]);
    bf16x8 pf = __builtin_bit_cast(bf16x8, pw);
    // ctx += P V over this kv half
    __builtin_amdgcn_s_setprio(1);
    #pragma unroll
    for (int nt = 0; nt < 4; ++nt) {
      int rowv = nt * 16 + ml;
      int p = (g * 4 + kg) ^ fsw(rowv);
      bf16x8 vf = *(const bf16x8*)(&Vh[rowv * 64 + p * 8]);
      ctx[nt] = mfma16(pf, vf, ctx[nt]);
    }
    __builtin_amdgcn_s_setprio(0);
    if (tt + 1 < NT) __syncthreads();  // staged loads landed; all waves done with cur
  }
  // combine wave-pair partials (g=1 -> g=0) through dead K/V LDS
  __syncthreads();
  float* comb = (float*)&Kl[0][0];   // [4 qs][16][64 lanes] f32 = 16KB
  float* psA = (float*)&Vl[0][0];    // [4 qs][64 lanes]
  if (g == 1) {
    int base = qs * 1024 + lane;
    #pragma unroll
    for (int nt = 0; nt < 4; ++nt)
      #pragma unroll
      for (int r = 0; r < 4; ++r)
        comb[base + (nt * 4 + r) * 64] = ctx[nt][r];
    psA[qs * 64 + lane] = psum;
  }
  __syncthreads();
  if (g == 0) {
    int base = qs * 1024 + lane;
    #pragma unroll
    for (int nt = 0; nt < 4; ++nt)
      #pragma unroll
      for (int r = 0; r < 4; ++r)
        ctx[nt][r] += comb[base + (nt * 4 + r) * 64];
    psum += psA[qs * 64 + lane];
    psum += __shfl_xor(psum, 16);
    psum += __shfl_xor(psum, 32);
    float inv[4];
    #pragma unroll
    for (int r = 0; r < 4; ++r) inv[r] = 1.f / __shfl(psum, kg * 4 + r);
    #pragma unroll
    for (int nt = 0; nt < 4; ++nt)
      #pragma unroll
      for (int r = 0; r < 4; ++r) {
        size_t row = (size_t)b * Ln + qt * 64 + qs * 16 + kg * 4 + r;
        att[row * Cn + h * Dn + nt * 16 + ml] = f2bfu(ctx[nt][r] * inv[r]);
      }
  }
}

// ---------------------------------------------------------------------------
// K6: h = xT + att ; LayerNorm over C ; out f32 [B][L][C]. grid (B*L)
__global__ __launch_bounds__(256) void ln_kernel(const u16* __restrict__ att,
                                                 const u16* __restrict__ xT,
                                                 const float* __restrict__ gamma,
                                                 const float* __restrict__ beta,
                                                 float* __restrict__ out) {
  size_t row = blockIdx.x;
  const u16* ap = att + row * Cn;
  const u16* xp = xT + row * Cn;
  float* op = out + row * Cn;
  int t = threadIdx.x;
  ushort4 a4 = *(const ushort4*)(ap + t * 4);
  ushort4 xv = *(const ushort4*)(xp + t * 4);
  float h0 = bfu2f(a4.x) + bfu2f(xv.x), h1 = bfu2f(a4.y) + bfu2f(xv.y);
  float h2 = bfu2f(a4.z) + bfu2f(xv.z), h3 = bfu2f(a4.w) + bfu2f(xv.w);
  float s = h0 + h1 + h2 + h3;
  float ss = h0 * h0 + h1 * h1 + h2 * h2 + h3 * h3;
  #pragma unroll
  for (int off = 1; off < 64; off <<= 1) {
    s += __shfl_xor(s, off);
    ss += __shfl_xor(ss, off);
  }
  __shared__ float red[8];
  int wave = t >> 6, lane = t & 63;
  if (lane == 0) { red[wave] = s; red[wave + 4] = ss; }
  __syncthreads();
  s = red[0] + red[1] + red[2] + red[3];
  ss = red[4] + red[5] + red[6] + red[7];
  float mu = s * (1.f / 1024.f);
  float var = ss * (1.f / 1024.f) - mu * mu;
  float rinv = rsqrtf(var + 1e-5f);
  float4 gmv = *(const float4*)(gamma + t * 4);
  float4 bev = *(const float4*)(beta + t * 4);
  float4 o;
  o.x = (h0 - mu) * rinv * gmv.x + bev.x;
  o.y = (h1 - mu) * rinv * gmv.y + bev.y;
  o.z = (h2 - mu) * rinv * gmv.z + bev.z;
  o.w = (h3 - mu) * rinv * gmv.w + bev.w;
  *(float4*)(op + t * 4) = o;
}

// ---------------------------------------------------------------------------
extern "C" void kernel_launch(void* const* d_in, const int* in_sizes, int n_in,
                              void* d_out, int out_size, void* d_ws, size_t ws_size,
                              hipStream_t stream) {
  const float* x = (const float*)d_in[0];
  const float* y = (const float*)d_in[1];
  const float* Wq = (const float*)d_in[2];
  const float* Wk = (const float*)d_in[3];
  const float* Wv = (const float*)d_in[4];
  const float* bq = (const float*)d_in[5];
  const float* bk = (const float*)d_in[6];
  const float* bv = (const float*)d_in[7];
  const float* gamma = (const float*)d_in[8];
  const float* beta = (const float*)d_in[9];
  float* out = (float*)d_out;

  char* ws = (char*)d_ws;
  u16* xT = (u16*)(ws + 0);               // 8388608 B
  u16* yT = (u16*)(ws + 8388608);         // 8388608 B
  u16* WT = (u16*)(ws + 16777216);        // 6291456 B
  u16* Qb = (u16*)(ws + 23068672);        // 8388608 B
  u16* Kb = (u16*)(ws + 31457280);        // 8388608 B
  u16* VT = (u16*)(ws + 39845888);        // 8388608 B
  u16* att = (u16*)(ws + 48234496);       // 8388608 B (end 56623104)

  transpose_xy<<<dim3(Ln / 64, Cn / 64, 4), dim3(256), 0, stream>>>(x, y, xT, yT);
  transpose_w<<<dim3(Cn / 64, Hn, 3), dim3(256), 0, stream>>>(Wq, Wk, Wv, WT);
  gemm_qkv3<<<dim3(Ln / 128, 24, Bn), dim3(256), 0, stream>>>(xT, yT, WT, bq, bk, bv, Qb, Kb, VT);
  flash_attn<<<dim3(Ln / 64, Hn, Bn), dim3(512), 0, stream>>>(Qb, Kb, VT, att);
  ln_kernel<<<dim3(Bn * Ln), dim3(256), 0, stream>>>(att, xT, gamma, beta, out);
}

// Round 8
// 108.505 us; speedup vs baseline: 1.9626x; 1.0120x over previous
//
#include <hip/hip_runtime.h>
#include <hip/hip_bf16.h>

#define DEVI __device__ __forceinline__

typedef unsigned short u16;
typedef __bf16 bf16x8 __attribute__((ext_vector_type(8)));
typedef float f32x4 __attribute__((ext_vector_type(4)));

constexpr int Bn = 2, Cn = 1024, Ln = 2048, Hn = 16, Dn = 64;

DEVI u16 f2bfu(float f) { return __builtin_bit_cast(u16, __float2bfloat16(f)); }
DEVI float bfu2f(u16 u) { return __bfloat162float(__builtin_bit_cast(__hip_bfloat16, u)); }
DEVI f32x4 mfma16(bf16x8 a, bf16x8 b, f32x4 c) {
  return __builtin_amdgcn_mfma_f32_16x16x32_bf16(a, b, c, 0, 0, 0);
}
DEVI unsigned pk2(float lo, float hi) {
  return (unsigned)f2bfu(lo) | ((unsigned)f2bfu(hi) << 16);
}
// async global->LDS, 16B per lane; LDS dest base must be wave-uniform,
// HW adds lane*16. Global source is per-lane (pre-swizzled upstream).
DEVI void gld16(const u16* g, u16* l) {
  __builtin_amdgcn_global_load_lds(
      (const __attribute__((address_space(1))) unsigned*)g,
      (__attribute__((address_space(3))) unsigned*)l, 16, 0, 0);
}
// LDS bank swizzle: fold row bit3 into bank-bit2 so permuted-row reads
// (which fix row&7 to 4 values) still spread over 8 bank-groups.
DEVI int fsw(int row) { return (row & 7) ^ (((row >> 3) & 1) << 2); }

// ---------------------------------------------------------------------------
// K1: transpose x,y [B][C][L] f32 -> xT,yT [B][L][C] bf16
// grid (L/64, C/64, 4) z = which*2 + b
__global__ __launch_bounds__(256) void transpose_xy(const float* __restrict__ x,
                                                    const float* __restrict__ y,
                                                    u16* __restrict__ xT,
                                                    u16* __restrict__ yT) {
  int z = blockIdx.z;
  int which = z >> 1, b = z & 1;
  const float* src = (which ? y : x) + (size_t)b * Cn * Ln;
  u16* dst = (which ? yT : xT) + (size_t)b * Ln * Cn;
  int l0 = blockIdx.x * 64, c0 = blockIdx.y * 64;
  __shared__ float tile[64][65];
  int t = threadIdx.x;
  #pragma unroll
  for (int i = 0; i < 16; ++i) {
    int idx = i * 256 + t;
    int r = idx >> 6, cc = idx & 63;  // r: c-row, cc: l-col
    tile[r][cc] = src[(size_t)(c0 + r) * Ln + (l0 + cc)];
  }
  __syncthreads();
  // store: pack 2 bf16 per thread -> 4B/lane coalesced
  #pragma unroll
  for (int i = 0; i < 8; ++i) {
    int idx = i * 256 + t;
    int r = idx >> 5, cc = (idx & 31) * 2;  // r: l-row, cc: c-col
    unsigned pkv = pk2(tile[cc][r], tile[cc + 1][r]);
    *(unsigned*)(&dst[(size_t)(l0 + r) * Cn + (c0 + cc)]) = pkv;
  }
}

// ---------------------------------------------------------------------------
// K2: transpose Wq/Wk/Wv [H][C][D] f32 -> WT [3][H][D][C] bf16
// grid (C/64, H, 3)
__global__ __launch_bounds__(256) void transpose_w(const float* __restrict__ Wq,
                                                   const float* __restrict__ Wk,
                                                   const float* __restrict__ Wv,
                                                   u16* __restrict__ WT) {
  int c0 = blockIdx.x * 64, h = blockIdx.y, which = blockIdx.z;
  const float* src = (which == 0 ? Wq : (which == 1 ? Wk : Wv)) + (size_t)h * Cn * Dn;
  u16* dst = WT + ((size_t)which * Hn + h) * Dn * Cn;
  __shared__ float tile[64][65];
  int t = threadIdx.x;
  #pragma unroll
  for (int i = 0; i < 16; ++i) {
    int idx = i * 256 + t;
    int r = idx >> 6, cc = idx & 63;  // r: c-row, cc: d-col
    tile[r][cc] = src[(size_t)(c0 + r) * Dn + cc];
  }
  __syncthreads();
  #pragma unroll
  for (int i = 0; i < 16; ++i) {
    int idx = i * 256 + t;
    int r = idx >> 6, cc = idx & 63;  // r: d-row, cc: c-col
    dst[(size_t)r * Cn + (c0 + cc)] = f2bfu(tile[cc][r]);
  }
}

// ---------------------------------------------------------------------------
// K3: fused QKV GEMM. O[l,n] = sum_c A[l,c]*W[n,c] + bias[n]
// A bf16 [B][L][C] (xT for Q, yT for K/V); W = WT [3][1024 rows][C].
// grid (L/128, 24, B): by -> which = by>>3, hp = by&7 (heads 2hp, 2hp+1).
// 4 waves (2x2), BM=128 BN=128 BK=64. Staging via global_load_lds (16B).
// Q/K written [B][H][L][D]; V written TRANSPOSED [B][H][D][L] via smem bounce.
__global__ __launch_bounds__(256) void gemm_qkv3(const u16* __restrict__ xT,
                                                 const u16* __restrict__ yT,
                                                 const u16* __restrict__ WT,
                                                 const float* __restrict__ bq,
                                                 const float* __restrict__ bk,
                                                 const float* __restrict__ bv,
                                                 u16* __restrict__ Qb,
                                                 u16* __restrict__ Kb,
                                                 u16* __restrict__ Vt) {
  int mt = blockIdx.x, by = blockIdx.y, b = blockIdx.z;
  int which = by >> 3, hp = by & 7;
  const u16* A = (which == 0 ? xT : yT) + (size_t)b * Ln * Cn + (size_t)mt * 128 * Cn;
  const u16* Bw = WT + ((size_t)which * 1024 + (size_t)hp * 128) * Cn;
  __shared__ __align__(16) u16 smem[2 * 128 * 64];  // lA | lB; reused as 128x128 for V transpose
  u16* lA = smem;
  u16* lB = smem + 128 * 64;
  int t = threadIdx.x, wave = t >> 6, lane = t & 63;
  int wr = wave >> 1, wc = wave & 1;
  int ml = lane & 15, kg = lane >> 4;
  f32x4 acc[4][4] = {};
  for (int k0 = 0; k0 < Cn; k0 += 64) {
    __syncthreads();
    // stage A,B (each 128x64): 1024 16B-chunks each, 4 gload_lds calls/wave
    #pragma unroll
    for (int j = 0; j < 4; ++j) {
      int q = wave * 256 + j * 64 + lane;
      int row = q >> 3, p = q & 7, c16 = p ^ (row & 7);
      gld16(A + (size_t)row * Cn + k0 + c16 * 8, &lA[(wave * 256 + j * 64) * 8]);
    }
    #pragma unroll
    for (int j = 0; j < 4; ++j) {
      int q = wave * 256 + j * 64 + lane;
      int row = q >> 3, p = q & 7, c16 = p ^ (row & 7);
      gld16(Bw + (size_t)row * Cn + k0 + c16 * 8, &lB[(wave * 256 + j * 64) * 8]);
    }
    __syncthreads();
    bf16x8 af[4][2], bf[4][2];
    #pragma unroll
    for (int m = 0; m < 4; ++m) {
      int row = wr * 64 + m * 16 + ml;
      #pragma unroll
      for (int kk = 0; kk < 2; ++kk) {
        int p = (kk * 4 + kg) ^ (row & 7);
        af[m][kk] = *(const bf16x8*)(&lA[row * 64 + p * 8]);
      }
    }
    #pragma unroll
    for (int n = 0; n < 4; ++n) {
      int row = wc * 64 + n * 16 + ml;
      #pragma unroll
      for (int kk = 0; kk < 2; ++kk) {
        int p = (kk * 4 + kg) ^ (row & 7);
        bf[n][kk] = *(const bf16x8*)(&lB[row * 64 + p * 8]);
      }
    }
    __builtin_amdgcn_s_setprio(1);
    #pragma unroll
    for (int m = 0; m < 4; ++m)
      #pragma unroll
      for (int n = 0; n < 4; ++n)
        #pragma unroll
        for (int kk = 0; kk < 2; ++kk)
          acc[m][n] = mfma16(af[m][kk], bf[n][kk], acc[m][n]);
    __builtin_amdgcn_s_setprio(0);
  }
  int head = hp * 2 + wc;
  const float* bp = (which == 0 ? bq : (which == 1 ? bk : bv));
  if (which < 2) {
    u16* O = (which == 0 ? Qb : Kb) + (((size_t)b * Hn + head) * Ln + (size_t)mt * 128) * Dn;
    #pragma unroll
    for (int n = 0; n < 4; ++n) {
      float bvv = bp[head * 64 + n * 16 + ml];
      #pragma unroll
      for (int m = 0; m < 4; ++m)
        #pragma unroll
        for (int r = 0; r < 4; ++r) {
          int row = wr * 64 + m * 16 + kg * 4 + r;
          O[(size_t)row * Dn + n * 16 + ml] = f2bfu(acc[m][n][r] + bvv);
        }
    }
  } else {
    // V: transpose through smem (128 l x 128 n), write VT [B][H][D][L]
    __syncthreads();  // all waves done with lA/lB fragments
    #pragma unroll
    for (int n = 0; n < 4; ++n) {
      float bvv = bp[head * 64 + n * 16 + ml];
      int n_loc = wc * 64 + n * 16 + ml;
      int swz = (n_loc & 7) << 4;
      #pragma unroll
      for (int m = 0; m < 4; ++m) {
        int m_base = wr * 64 + m * 16 + kg * 4;
        uint2 pkd;
        pkd.x = pk2(acc[m][n][0] + bvv, acc[m][n][1] + bvv);
        pkd.y = pk2(acc[m][n][2] + bvv, acc[m][n][3] + bvv);
        *(uint2*)(&smem[n_loc * 128 + (m_base ^ swz)]) = pkd;
      }
    }
    __syncthreads();
    u16* Vbase = Vt + ((size_t)b * Hn + hp * 2) * Dn * Ln + (size_t)mt * 128;
    #pragma unroll
    for (int i = 0; i < 8; ++i) {
      int chunk = i * 256 + t;
      int n = chunk >> 4, cc = chunk & 15;
      uint4 vv = *(const uint4*)(&smem[n * 128 + (cc ^ ((n & 7) << 1)) * 8]);
      *(uint4*)(Vbase + (size_t)n * Ln + cc * 8) = vv;  // n = h2*64+d; row stride Ln
    }
  }
}

// ---------------------------------------------------------------------------
// K5: flash attention v7: v6 + counted-vmcnt two-barrier pipeline (T3/T4).
// Per tile: stage(next) -> vmcnt(2)+barrier (current tile's loads landed,
// next tile's 2 stay in flight) -> compute -> lgkmcnt(0)+barrier (release buf).
// Last tile waits vmcnt(0) (its own loads are the outstanding ones).
// kv-permuted QK output keeps P in registers; fsw LDS swizzle; XCD remap.
// grid (L/64, H, B) remapped in-kernel. out att bf16 [B][L][H*D].
__global__ __launch_bounds__(512, 8) void flash_attn(const u16* __restrict__ Qg,
                                                     const u16* __restrict__ Kg,
                                                     const u16* __restrict__ Vtg,
                                                     u16* __restrict__ att) {
  // --- XCD-aware remap (8 XCDs, 1024 blocks, HW assigns n%8) ---
  int n = blockIdx.x + 32 * (blockIdx.y + 16 * blockIdx.z);
  int xcd = n & 7, m = n >> 3;
  int grp = xcd * 4 + (m >> 5);       // 0..31 -> (b,h)
  int qt = m & 31;
  int h = grp & 15, b = grp >> 4;

  size_t bh = (size_t)b * Hn + h;
  const u16* Qp = Qg + (bh * Ln + (size_t)qt * 64) * Dn;
  const u16* Kp = Kg + bh * Ln * Dn;
  const u16* Vp = Vtg + bh * Dn * Ln;
  int t = threadIdx.x, wave = t >> 6, lane = t & 63;
  int qs = wave & 3, g = wave >> 2;       // q-slice, kv-half
  int ml = lane & 15, kg = lane >> 4;
  __shared__ __align__(16) u16 Kl[2][64 * 64];   // [kv 64][d 64] fsw-swizzled
  __shared__ __align__(16) u16 Vl[2][64 * 64];   // [d 64][kv 64] fsw-swizzled

  constexpr float QS = 0.125f * 1.44269504f;  // softmax scale + log2(e) folded into Q
  bf16x8 qf[2];
  #pragma unroll
  for (int kk = 0; kk < 2; ++kk) {
    bf16x8 raw = *(const bf16x8*)(Qp + (size_t)(qs * 16 + ml) * Dn + kk * 32 + kg * 8);
    #pragma unroll
    for (int j = 0; j < 8; ++j) raw[j] = (__bf16)((float)raw[j] * QS);
    qf[kk] = raw;
  }

  f32x4 ctx[4] = {};
  float psum = 0.f;

  // hoisted per-lane LDS element offsets (loop-invariant)
  int koff[2][2], voff[4];
  {
    #pragma unroll
    for (int nt = 0; nt < 2; ++nt) {
      int rowk = g * 32 + 8 * (ml >> 2) + 4 * nt + (ml & 3);
      #pragma unroll
      for (int kk = 0; kk < 2; ++kk)
        koff[nt][kk] = rowk * 64 + (((kk * 4 + kg) ^ fsw(rowk)) << 3);
    }
    #pragma unroll
    for (int nt = 0; nt < 4; ++nt) {
      int rowv = nt * 16 + ml;
      voff[nt] = rowv * 64 + ((((g * 4 + kg) ^ fsw(rowv))) << 3);
    }
  }
  // hoisted per-lane global stage offsets (only kv0 varies per tile)
  int rowk_st = t >> 3;
  int c16_st = ((t & 7) ^ fsw(rowk_st)) * 8;

  // 512 threads stage one 16B chunk each per buffer (64x64 u16 = 512 chunks)
  auto stage = [&](int buf, int kv0) {
    gld16(Kp + (size_t)(kv0 + rowk_st) * Dn + c16_st, &Kl[buf][wave * 512]);
    gld16(Vp + (size_t)rowk_st * Ln + kv0 + c16_st, &Vl[buf][wave * 512]);
  };

  constexpr int NT = Ln / 64;

  auto tile = [&](int cur, int tt) {
    if (tt + 1 < NT) {
      stage(cur ^ 1, (tt + 1) * 64);  // 2 VMEM ops stay in flight across barrier
      asm volatile("s_waitcnt vmcnt(2)" ::: "memory");
    } else {
      asm volatile("s_waitcnt vmcnt(0)" ::: "memory");
    }
    __builtin_amdgcn_s_barrier();        // B: all waves' tile-tt loads landed
    __builtin_amdgcn_sched_barrier(0);
    const u16* Kh = Kl[cur];
    const u16* Vh = Vl[cur];
    // S^T = K.Q^T, kv-permuted A-rows: lane (ml,kg) reg r of subtile nt holds
    // kv = g*32 + kg*8 + nt*4 + r  (contiguous 8 kv per lane across nt)
    f32x4 s[2] = {};
    __builtin_amdgcn_s_setprio(1);
    #pragma unroll
    for (int nt = 0; nt < 2; ++nt)
      #pragma unroll
      for (int kk = 0; kk < 2; ++kk) {
        bf16x8 kf = *(const bf16x8*)(&Kh[koff[nt][kk]]);
        s[nt] = mfma16(kf, qf[kk], s[nt]);
      }
    __builtin_amdgcn_s_setprio(0);
    // P = exp2(S), packed straight into the PV A-fragment (registers only)
    f32x4 e0, e1;
    #pragma unroll
    for (int r = 0; r < 4; ++r) e0[r] = __builtin_amdgcn_exp2f(s[0][r]);
    #pragma unroll
    for (int r = 0; r < 4; ++r) e1[r] = __builtin_amdgcn_exp2f(s[1][r]);
    psum += (e0[0] + e0[1]) + (e0[2] + e0[3]) + (e1[0] + e1[1]) + (e1[2] + e1[3]);
    uint4 pw;
    pw.x = pk2(e0[0], e0[1]);
    pw.y = pk2(e0[2], e0[3]);
    pw.z = pk2(e1[0], e1[1]);
    pw.w = pk2(e1[2], e1[3]);
    bf16x8 pf = __builtin_bit_cast(bf16x8, pw);
    // ctx += P V over this kv half
    __builtin_amdgcn_s_setprio(1);
    #pragma unroll
    for (int nt = 0; nt < 4; ++nt) {
      bf16x8 vf = *(const bf16x8*)(&Vh[voff[nt]]);
      ctx[nt] = mfma16(pf, vf, ctx[nt]);
    }
    __builtin_amdgcn_s_setprio(0);
    asm volatile("s_waitcnt lgkmcnt(0)" ::: "memory");
    __builtin_amdgcn_s_barrier();        // A: release buffer cur (no vm drain)
  };

  stage(0, 0);
  asm volatile("s_waitcnt vmcnt(0)" ::: "memory");
  __builtin_amdgcn_s_barrier();

  for (int tt = 0; tt < NT; tt += 2) {
    tile(0, tt);
    tile(1, tt + 1);
  }

  // combine wave-pair partials (g=1 -> g=0) through dead K/V LDS
  __syncthreads();
  float* comb = (float*)&Kl[0][0];   // [4 qs][16][64 lanes] f32 = 16KB
  float* psA = (float*)&Vl[0][0];    // [4 qs][64 lanes]
  if (g == 1) {
    int base = qs * 1024 + lane;
    #pragma unroll
    for (int nt = 0; nt < 4; ++nt)
      #pragma unroll
      for (int r = 0; r < 4; ++r)
        comb[base + (nt * 4 + r) * 64] = ctx[nt][r];
    psA[qs * 64 + lane] = psum;
  }
  __syncthreads();
  if (g == 0) {
    int base = qs * 1024 + lane;
    #pragma unroll
    for (int nt = 0; nt < 4; ++nt)
      #pragma unroll
      for (int r = 0; r < 4; ++r)
        ctx[nt][r] += comb[base + (nt * 4 + r) * 64];
    psum += psA[qs * 64 + lane];
    psum += __shfl_xor(psum, 16);
    psum += __shfl_xor(psum, 32);
    float inv[4];
    #pragma unroll
    for (int r = 0; r < 4; ++r) inv[r] = 1.f / __shfl(psum, kg * 4 + r);
    #pragma unroll
    for (int nt = 0; nt < 4; ++nt)
      #pragma unroll
      for (int r = 0; r < 4; ++r) {
        size_t row = (size_t)b * Ln + qt * 64 + qs * 16 + kg * 4 + r;
        att[row * Cn + h * Dn + nt * 16 + ml] = f2bfu(ctx[nt][r] * inv[r]);
      }
  }
}

// ---------------------------------------------------------------------------
// K6: h = xT + att ; LayerNorm over C ; out f32 [B][L][C]. grid (B*L)
__global__ __launch_bounds__(256) void ln_kernel(const u16* __restrict__ att,
                                                 const u16* __restrict__ xT,
                                                 const float* __restrict__ gamma,
                                                 const float* __restrict__ beta,
                                                 float* __restrict__ out) {
  size_t row = blockIdx.x;
  const u16* ap = att + row * Cn;
  const u16* xp = xT + row * Cn;
  float* op = out + row * Cn;
  int t = threadIdx.x;
  ushort4 a4 = *(const ushort4*)(ap + t * 4);
  ushort4 xv = *(const ushort4*)(xp + t * 4);
  float h0 = bfu2f(a4.x) + bfu2f(xv.x), h1 = bfu2f(a4.y) + bfu2f(xv.y);
  float h2 = bfu2f(a4.z) + bfu2f(xv.z), h3 = bfu2f(a4.w) + bfu2f(xv.w);
  float s = h0 + h1 + h2 + h3;
  float ss = h0 * h0 + h1 * h1 + h2 * h2 + h3 * h3;
  #pragma unroll
  for (int off = 1; off < 64; off <<= 1) {
    s += __shfl_xor(s, off);
    ss += __shfl_xor(ss, off);
  }
  __shared__ float red[8];
  int wave = t >> 6, lane = t & 63;
  if (lane == 0) { red[wave] = s; red[wave + 4] = ss; }
  __syncthreads();
  s = red[0] + red[1] + red[2] + red[3];
  ss = red[4] + red[5] + red[6] + red[7];
  float mu = s * (1.f / 1024.f);
  float var = ss * (1.f / 1024.f) - mu * mu;
  float rinv = rsqrtf(var + 1e-5f);
  float4 gmv = *(const float4*)(gamma + t * 4);
  float4 bev = *(const float4*)(beta + t * 4);
  float4 o;
  o.x = (h0 - mu) * rinv * gmv.x + bev.x;
  o.y = (h1 - mu) * rinv * gmv.y + bev.y;
  o.z = (h2 - mu) * rinv * gmv.z + bev.z;
  o.w = (h3 - mu) * rinv * gmv.w + bev.w;
  *(float4*)(op + t * 4) = o;
}

// ---------------------------------------------------------------------------
extern "C" void kernel_launch(void* const* d_in, const int* in_sizes, int n_in,
                              void* d_out, int out_size, void* d_ws, size_t ws_size,
                              hipStream_t stream) {
  const float* x = (const float*)d_in[0];
  const float* y = (const float*)d_in[1];
  const float* Wq = (const float*)d_in[2];
  const float* Wk = (const float*)d_in[3];
  const float* Wv = (const float*)d_in[4];
  const float* bq = (const float*)d_in[5];
  const float* bk = (const float*)d_in[6];
  const float* bv = (const float*)d_in[7];
  const float* gamma = (const float*)d_in[8];
  const float* beta = (const float*)d_in[9];
  float* out = (float*)d_out;

  char* ws = (char*)d_ws;
  u16* xT = (u16*)(ws + 0);               // 8388608 B
  u16* yT = (u16*)(ws + 8388608);         // 8388608 B
  u16* WT = (u16*)(ws + 16777216);        // 6291456 B
  u16* Qb = (u16*)(ws + 23068672);        // 8388608 B
  u16* Kb = (u16*)(ws + 31457280);        // 8388608 B
  u16* VT = (u16*)(ws + 39845888);        // 8388608 B
  u16* att = (u16*)(ws + 48234496);       // 8388608 B (end 56623104)

  transpose_xy<<<dim3(Ln / 64, Cn / 64, 4), dim3(256), 0, stream>>>(x, y, xT, yT);
  transpose_w<<<dim3(Cn / 64, Hn, 3), dim3(256), 0, stream>>>(Wq, Wk, Wv, WT);
  gemm_qkv3<<<dim3(Ln / 128, 24, Bn), dim3(256), 0, stream>>>(xT, yT, WT, bq, bk, bv, Qb, Kb, VT);
  flash_attn<<<dim3(Ln / 64, Hn, Bn), dim3(512), 0, stream>>>(Qb, Kb, VT, att);
  ln_kernel<<<dim3(Bn * Ln), dim3(256), 0, stream>>>(att, xT, gamma, beta, out);
}

// Round 9
// 106.470 us; speedup vs baseline: 2.0001x; 1.0191x over previous
//
#include <hip/hip_runtime.h>
#include <hip/hip_bf16.h>

#define DEVI __device__ __forceinline__

typedef unsigned short u16;
typedef __bf16 bf16x8 __attribute__((ext_vector_type(8)));
typedef float f32x4 __attribute__((ext_vector_type(4)));

constexpr int Bn = 2, Cn = 1024, Ln = 2048, Hn = 16, Dn = 64;

DEVI u16 f2bfu(float f) { return __builtin_bit_cast(u16, __float2bfloat16(f)); }
DEVI float bfu2f(u16 u) { return __bfloat162float(__builtin_bit_cast(__hip_bfloat16, u)); }
DEVI f32x4 mfma16(bf16x8 a, bf16x8 b, f32x4 c) {
  return __builtin_amdgcn_mfma_f32_16x16x32_bf16(a, b, c, 0, 0, 0);
}
DEVI unsigned pk2(float lo, float hi) {
  return (unsigned)f2bfu(lo) | ((unsigned)f2bfu(hi) << 16);
}
// async global->LDS, 16B per lane; LDS dest base must be wave-uniform,
// HW adds lane*16. Global source is per-lane (pre-swizzled upstream).
DEVI void gld16(const u16* g, u16* l) {
  __builtin_amdgcn_global_load_lds(
      (const __attribute__((address_space(1))) unsigned*)g,
      (__attribute__((address_space(3))) unsigned*)l, 16, 0, 0);
}
// LDS bank swizzle: fold row bit3 into bank-bit2 so permuted-row reads
// (which fix row&7 to 4 values) still spread over 8 bank-groups.
DEVI int fsw(int row) { return (row & 7) ^ (((row >> 3) & 1) << 2); }

// ---------------------------------------------------------------------------
// K1: transpose x,y [B][C][L] f32 -> xT,yT [B][L][C] bf16
// grid (L/64, C/64, 4) z = which*2 + b
__global__ __launch_bounds__(256) void transpose_xy(const float* __restrict__ x,
                                                    const float* __restrict__ y,
                                                    u16* __restrict__ xT,
                                                    u16* __restrict__ yT) {
  int z = blockIdx.z;
  int which = z >> 1, b = z & 1;
  const float* src = (which ? y : x) + (size_t)b * Cn * Ln;
  u16* dst = (which ? yT : xT) + (size_t)b * Ln * Cn;
  int l0 = blockIdx.x * 64, c0 = blockIdx.y * 64;
  __shared__ float tile[64][65];
  int t = threadIdx.x;
  #pragma unroll
  for (int i = 0; i < 16; ++i) {
    int idx = i * 256 + t;
    int r = idx >> 6, cc = idx & 63;  // r: c-row, cc: l-col
    tile[r][cc] = src[(size_t)(c0 + r) * Ln + (l0 + cc)];
  }
  __syncthreads();
  // store: pack 2 bf16 per thread -> 4B/lane coalesced
  #pragma unroll
  for (int i = 0; i < 8; ++i) {
    int idx = i * 256 + t;
    int r = idx >> 5, cc = (idx & 31) * 2;  // r: l-row, cc: c-col
    unsigned pkv = pk2(tile[cc][r], tile[cc + 1][r]);
    *(unsigned*)(&dst[(size_t)(l0 + r) * Cn + (c0 + cc)]) = pkv;
  }
}

// ---------------------------------------------------------------------------
// K2: transpose Wq/Wk/Wv [H][C][D] f32 -> WT [3][H][D][C] bf16
// grid (C/64, H, 3)
__global__ __launch_bounds__(256) void transpose_w(const float* __restrict__ Wq,
                                                   const float* __restrict__ Wk,
                                                   const float* __restrict__ Wv,
                                                   u16* __restrict__ WT) {
  int c0 = blockIdx.x * 64, h = blockIdx.y, which = blockIdx.z;
  const float* src = (which == 0 ? Wq : (which == 1 ? Wk : Wv)) + (size_t)h * Cn * Dn;
  u16* dst = WT + ((size_t)which * Hn + h) * Dn * Cn;
  __shared__ float tile[64][65];
  int t = threadIdx.x;
  #pragma unroll
  for (int i = 0; i < 16; ++i) {
    int idx = i * 256 + t;
    int r = idx >> 6, cc = idx & 63;  // r: c-row, cc: d-col
    tile[r][cc] = src[(size_t)(c0 + r) * Dn + cc];
  }
  __syncthreads();
  #pragma unroll
  for (int i = 0; i < 16; ++i) {
    int idx = i * 256 + t;
    int r = idx >> 6, cc = idx & 63;  // r: d-row, cc: c-col
    dst[(size_t)r * Cn + (c0 + cc)] = f2bfu(tile[cc][r]);
  }
}

// ---------------------------------------------------------------------------
// K3: fused QKV GEMM. O[l,n] = sum_c A[l,c]*W[n,c] + bias[n]
// A bf16 [B][L][C] (xT for Q, yT for K/V); W = WT [3][1024 rows][C].
// grid (L/128, 24, B): by -> which = by>>3, hp = by&7 (heads 2hp, 2hp+1).
// 4 waves (2x2), BM=128 BN=128 BK=64. Staging via global_load_lds (16B).
// Q/K written [B][H][L][D]; V written TRANSPOSED [B][H][D][L] via smem bounce.
__global__ __launch_bounds__(256) void gemm_qkv3(const u16* __restrict__ xT,
                                                 const u16* __restrict__ yT,
                                                 const u16* __restrict__ WT,
                                                 const float* __restrict__ bq,
                                                 const float* __restrict__ bk,
                                                 const float* __restrict__ bv,
                                                 u16* __restrict__ Qb,
                                                 u16* __restrict__ Kb,
                                                 u16* __restrict__ Vt) {
  int mt = blockIdx.x, by = blockIdx.y, b = blockIdx.z;
  int which = by >> 3, hp = by & 7;
  const u16* A = (which == 0 ? xT : yT) + (size_t)b * Ln * Cn + (size_t)mt * 128 * Cn;
  const u16* Bw = WT + ((size_t)which * 1024 + (size_t)hp * 128) * Cn;
  __shared__ __align__(16) u16 smem[2 * 128 * 64];  // lA | lB; reused as 128x128 for V transpose
  u16* lA = smem;
  u16* lB = smem + 128 * 64;
  int t = threadIdx.x, wave = t >> 6, lane = t & 63;
  int wr = wave >> 1, wc = wave & 1;
  int ml = lane & 15, kg = lane >> 4;
  f32x4 acc[4][4] = {};
  for (int k0 = 0; k0 < Cn; k0 += 64) {
    __syncthreads();
    // stage A,B (each 128x64): 1024 16B-chunks each, 4 gload_lds calls/wave
    #pragma unroll
    for (int j = 0; j < 4; ++j) {
      int q = wave * 256 + j * 64 + lane;
      int row = q >> 3, p = q & 7, c16 = p ^ (row & 7);
      gld16(A + (size_t)row * Cn + k0 + c16 * 8, &lA[(wave * 256 + j * 64) * 8]);
    }
    #pragma unroll
    for (int j = 0; j < 4; ++j) {
      int q = wave * 256 + j * 64 + lane;
      int row = q >> 3, p = q & 7, c16 = p ^ (row & 7);
      gld16(Bw + (size_t)row * Cn + k0 + c16 * 8, &lB[(wave * 256 + j * 64) * 8]);
    }
    __syncthreads();
    bf16x8 af[4][2], bf[4][2];
    #pragma unroll
    for (int m = 0; m < 4; ++m) {
      int row = wr * 64 + m * 16 + ml;
      #pragma unroll
      for (int kk = 0; kk < 2; ++kk) {
        int p = (kk * 4 + kg) ^ (row & 7);
        af[m][kk] = *(const bf16x8*)(&lA[row * 64 + p * 8]);
      }
    }
    #pragma unroll
    for (int n = 0; n < 4; ++n) {
      int row = wc * 64 + n * 16 + ml;
      #pragma unroll
      for (int kk = 0; kk < 2; ++kk) {
        int p = (kk * 4 + kg) ^ (row & 7);
        bf[n][kk] = *(const bf16x8*)(&lB[row * 64 + p * 8]);
      }
    }
    __builtin_amdgcn_s_setprio(1);
    #pragma unroll
    for (int m = 0; m < 4; ++m)
      #pragma unroll
      for (int n = 0; n < 4; ++n)
        #pragma unroll
        for (int kk = 0; kk < 2; ++kk)
          acc[m][n] = mfma16(af[m][kk], bf[n][kk], acc[m][n]);
    __builtin_amdgcn_s_setprio(0);
  }
  int head = hp * 2 + wc;
  const float* bp = (which == 0 ? bq : (which == 1 ? bk : bv));
  if (which < 2) {
    u16* O = (which == 0 ? Qb : Kb) + (((size_t)b * Hn + head) * Ln + (size_t)mt * 128) * Dn;
    #pragma unroll
    for (int n = 0; n < 4; ++n) {
      float bvv = bp[head * 64 + n * 16 + ml];
      #pragma unroll
      for (int m = 0; m < 4; ++m)
        #pragma unroll
        for (int r = 0; r < 4; ++r) {
          int row = wr * 64 + m * 16 + kg * 4 + r;
          O[(size_t)row * Dn + n * 16 + ml] = f2bfu(acc[m][n][r] + bvv);
        }
    }
  } else {
    // V: transpose through smem (128 l x 128 n), write VT [B][H][D][L]
    __syncthreads();  // all waves done with lA/lB fragments
    #pragma unroll
    for (int n = 0; n < 4; ++n) {
      float bvv = bp[head * 64 + n * 16 + ml];
      int n_loc = wc * 64 + n * 16 + ml;
      int swz = (n_loc & 7) << 4;
      #pragma unroll
      for (int m = 0; m < 4; ++m) {
        int m_base = wr * 64 + m * 16 + kg * 4;
        uint2 pkd;
        pkd.x = pk2(acc[m][n][0] + bvv, acc[m][n][1] + bvv);
        pkd.y = pk2(acc[m][n][2] + bvv, acc[m][n][3] + bvv);
        *(uint2*)(&smem[n_loc * 128 + (m_base ^ swz)]) = pkd;
      }
    }
    __syncthreads();
    u16* Vbase = Vt + ((size_t)b * Hn + hp * 2) * Dn * Ln + (size_t)mt * 128;
    #pragma unroll
    for (int i = 0; i < 8; ++i) {
      int chunk = i * 256 + t;
      int n = chunk >> 4, cc = chunk & 15;
      uint4 vv = *(const uint4*)(&smem[n * 128 + (cc ^ ((n & 7) << 1)) * 8]);
      *(uint4*)(Vbase + (size_t)n * Ln + cc * 8) = vv;  // n = h2*64+d; row stride Ln
    }
  }
}

// ---------------------------------------------------------------------------
// K5: flash attention v8: 32 q-rows per wave -> K/V LDS fragments reused
// across 2 q-groups (8 B/q·kv vs 16; kernel was LDS-BW-bound).
// 4 waves (256 thr): wave (qs,g) = (wave&1, wave>>1); qs = 32-q slice,
// g = kv half. Double-buffered K/V via global_load_lds, counted vmcnt(4),
// two barriers/tile. kv-permuted QK output keeps P in registers.
// fsw LDS swizzle; XCD remap. out att bf16 [B][L][H*D].
__global__ __launch_bounds__(256, 4) void flash_attn(const u16* __restrict__ Qg,
                                                     const u16* __restrict__ Kg,
                                                     const u16* __restrict__ Vtg,
                                                     u16* __restrict__ att) {
  // --- XCD-aware remap (8 XCDs, 1024 blocks, HW assigns n%8) ---
  int n = blockIdx.x + 32 * (blockIdx.y + 16 * blockIdx.z);
  int xcd = n & 7, m = n >> 3;
  int grp = xcd * 4 + (m >> 5);       // 0..31 -> (b,h)
  int qt = m & 31;
  int h = grp & 15, b = grp >> 4;

  size_t bh = (size_t)b * Hn + h;
  const u16* Qp = Qg + (bh * Ln + (size_t)qt * 64) * Dn;
  const u16* Kp = Kg + bh * Ln * Dn;
  const u16* Vp = Vtg + bh * Dn * Ln;
  int t = threadIdx.x, wave = t >> 6, lane = t & 63;
  int qs = wave & 1, g = wave >> 1;       // 32-q slice, kv-half
  int ml = lane & 15, kg = lane >> 4;
  __shared__ __align__(16) u16 Kl[2][64 * 64];   // [kv 64][d 64] fsw-swizzled
  __shared__ __align__(16) u16 Vl[2][64 * 64];   // [d 64][kv 64] fsw-swizzled

  constexpr float QS = 0.125f * 1.44269504f;  // softmax scale + log2(e) folded into Q
  bf16x8 qf[2][2];
  #pragma unroll
  for (int qg = 0; qg < 2; ++qg)
    #pragma unroll
    for (int kk = 0; kk < 2; ++kk) {
      bf16x8 raw = *(const bf16x8*)(Qp + (size_t)(qs * 32 + qg * 16 + ml) * Dn + kk * 32 + kg * 8);
      #pragma unroll
      for (int j = 0; j < 8; ++j) raw[j] = (__bf16)((float)raw[j] * QS);
      qf[qg][kk] = raw;
    }

  f32x4 ctx[2][4] = {};
  float psum[2] = {0.f, 0.f};

  // hoisted per-lane LDS element offsets (loop-invariant)
  int koff[2][2], voff[4];
  {
    #pragma unroll
    for (int nt = 0; nt < 2; ++nt) {
      int rowk = g * 32 + 8 * (ml >> 2) + 4 * nt + (ml & 3);
      #pragma unroll
      for (int kk = 0; kk < 2; ++kk)
        koff[nt][kk] = rowk * 64 + (((kk * 4 + kg) ^ fsw(rowk)) << 3);
    }
    #pragma unroll
    for (int nt = 0; nt < 4; ++nt) {
      int rowv = nt * 16 + ml;
      voff[nt] = rowv * 64 + ((((g * 4 + kg) ^ fsw(rowv))) << 3);
    }
  }
  // hoisted per-lane global stage offsets (only kv0 varies per tile)
  int row_st[2], c16_st[2];
  #pragma unroll
  for (int j = 0; j < 2; ++j) {
    int q = j * 256 + t;
    row_st[j] = q >> 3;
    c16_st[j] = ((q & 7) ^ fsw(row_st[j])) * 8;
  }

  // 256 threads stage 2 chunks each per matrix (64x64 u16 = 512 chunks)
  auto stage = [&](int buf, int kv0) {
    #pragma unroll
    for (int j = 0; j < 2; ++j)
      gld16(Kp + (size_t)(kv0 + row_st[j]) * Dn + c16_st[j],
            &Kl[buf][(j * 256 + wave * 64) * 8]);
    #pragma unroll
    for (int j = 0; j < 2; ++j)
      gld16(Vp + (size_t)row_st[j] * Ln + kv0 + c16_st[j],
            &Vl[buf][(j * 256 + wave * 64) * 8]);
  };

  constexpr int NT = Ln / 64;

  auto tile = [&](int cur, int tt) {
    if (tt + 1 < NT) {
      stage(cur ^ 1, (tt + 1) * 64);  // 4 VMEM ops stay in flight across barrier
      asm volatile("s_waitcnt vmcnt(4)" ::: "memory");
    } else {
      asm volatile("s_waitcnt vmcnt(0)" ::: "memory");
    }
    __builtin_amdgcn_s_barrier();        // B: all waves' tile-tt loads landed
    __builtin_amdgcn_sched_barrier(0);
    const u16* Kh = Kl[cur];
    const u16* Vh = Vl[cur];
    // S^T = K.Q^T, kv-permuted A-rows: lane (ml,kg) reg r of subtile nt holds
    // kv = g*32 + kg*8 + nt*4 + r. K frags shared by both q-groups.
    bf16x8 kf[2][2];
    #pragma unroll
    for (int nt = 0; nt < 2; ++nt)
      #pragma unroll
      for (int kk = 0; kk < 2; ++kk)
        kf[nt][kk] = *(const bf16x8*)(&Kh[koff[nt][kk]]);
    f32x4 s[2][2] = {};
    __builtin_amdgcn_s_setprio(1);
    #pragma unroll
    for (int nt = 0; nt < 2; ++nt)
      #pragma unroll
      for (int kk = 0; kk < 2; ++kk)
        #pragma unroll
        for (int qg = 0; qg < 2; ++qg)
          s[qg][nt] = mfma16(kf[nt][kk], qf[qg][kk], s[qg][nt]);
    __builtin_amdgcn_s_setprio(0);
    // P = exp2(S), packed straight into the PV A-fragment (registers only)
    bf16x8 pf[2];
    #pragma unroll
    for (int qg = 0; qg < 2; ++qg) {
      f32x4 e0, e1;
      #pragma unroll
      for (int r = 0; r < 4; ++r) e0[r] = __builtin_amdgcn_exp2f(s[qg][0][r]);
      #pragma unroll
      for (int r = 0; r < 4; ++r) e1[r] = __builtin_amdgcn_exp2f(s[qg][1][r]);
      psum[qg] += (e0[0] + e0[1]) + (e0[2] + e0[3]) + (e1[0] + e1[1]) + (e1[2] + e1[3]);
      uint4 pw;
      pw.x = pk2(e0[0], e0[1]);
      pw.y = pk2(e0[2], e0[3]);
      pw.z = pk2(e1[0], e1[1]);
      pw.w = pk2(e1[2], e1[3]);
      pf[qg] = __builtin_bit_cast(bf16x8, pw);
    }
    // ctx += P V over this kv half; V frags shared by both q-groups
    __builtin_amdgcn_s_setprio(1);
    #pragma unroll
    for (int nt = 0; nt < 4; ++nt) {
      bf16x8 vf = *(const bf16x8*)(&Vh[voff[nt]]);
      #pragma unroll
      for (int qg = 0; qg < 2; ++qg)
        ctx[qg][nt] = mfma16(pf[qg], vf, ctx[qg][nt]);
    }
    __builtin_amdgcn_s_setprio(0);
    asm volatile("s_waitcnt lgkmcnt(0)" ::: "memory");
    __builtin_amdgcn_s_barrier();        // A: release buffer cur (no vm drain)
  };

  stage(0, 0);
  asm volatile("s_waitcnt vmcnt(0)" ::: "memory");
  __builtin_amdgcn_s_barrier();

  for (int tt = 0; tt < NT; tt += 2) {
    tile(0, tt);
    tile(1, tt + 1);
  }

  // combine wave-pair partials (g=1 -> g=0) through dead K/V LDS
  __syncthreads();
  float* comb = (float*)&Kl[0][0];   // [qs2*qg2*16 rows][64 lanes] f32 = 16KB
  float* psA = (float*)&Vl[0][0];    // [qs2*qg2][64 lanes]
  if (g == 1) {
    #pragma unroll
    for (int qg = 0; qg < 2; ++qg) {
      #pragma unroll
      for (int nt = 0; nt < 4; ++nt)
        #pragma unroll
        for (int r = 0; r < 4; ++r)
          comb[(((qs * 2 + qg) * 16) + nt * 4 + r) * 64 + lane] = ctx[qg][nt][r];
      psA[(qs * 2 + qg) * 64 + lane] = psum[qg];
    }
  }
  __syncthreads();
  if (g == 0) {
    #pragma unroll
    for (int qg = 0; qg < 2; ++qg) {
      #pragma unroll
      for (int nt = 0; nt < 4; ++nt)
        #pragma unroll
        for (int r = 0; r < 4; ++r)
          ctx[qg][nt][r] += comb[(((qs * 2 + qg) * 16) + nt * 4 + r) * 64 + lane];
      psum[qg] += psA[(qs * 2 + qg) * 64 + lane];
      psum[qg] += __shfl_xor(psum[qg], 16);
      psum[qg] += __shfl_xor(psum[qg], 32);
    }
    #pragma unroll
    for (int qg = 0; qg < 2; ++qg) {
      float inv[4];
      #pragma unroll
      for (int r = 0; r < 4; ++r) inv[r] = 1.f / __shfl(psum[qg], kg * 4 + r);
      #pragma unroll
      for (int nt = 0; nt < 4; ++nt)
        #pragma unroll
        for (int r = 0; r < 4; ++r) {
          size_t row = (size_t)b * Ln + qt * 64 + qs * 32 + qg * 16 + kg * 4 + r;
          att[row * Cn + h * Dn + nt * 16 + ml] = f2bfu(ctx[qg][nt][r] * inv[r]);
        }
    }
  }
}

// ---------------------------------------------------------------------------
// K6: h = xT + att ; LayerNorm over C ; out f32 [B][L][C]. grid (B*L)
__global__ __launch_bounds__(256) void ln_kernel(const u16* __restrict__ att,
                                                 const u16* __restrict__ xT,
                                                 const float* __restrict__ gamma,
                                                 const float* __restrict__ beta,
                                                 float* __restrict__ out) {
  size_t row = blockIdx.x;
  const u16* ap = att + row * Cn;
  const u16* xp = xT + row * Cn;
  float* op = out + row * Cn;
  int t = threadIdx.x;
  ushort4 a4 = *(const ushort4*)(ap + t * 4);
  ushort4 xv = *(const ushort4*)(xp + t * 4);
  float h0 = bfu2f(a4.x) + bfu2f(xv.x), h1 = bfu2f(a4.y) + bfu2f(xv.y);
  float h2 = bfu2f(a4.z) + bfu2f(xv.z), h3 = bfu2f(a4.w) + bfu2f(xv.w);
  float s = h0 + h1 + h2 + h3;
  float ss = h0 * h0 + h1 * h1 + h2 * h2 + h3 * h3;
  #pragma unroll
  for (int off = 1; off < 64; off <<= 1) {
    s += __shfl_xor(s, off);
    ss += __shfl_xor(ss, off);
  }
  __shared__ float red[8];
  int wave = t >> 6, lane = t & 63;
  if (lane == 0) { red[wave] = s; red[wave + 4] = ss; }
  __syncthreads();
  s = red[0] + red[1] + red[2] + red[3];
  ss = red[4] + red[5] + red[6] + red[7];
  float mu = s * (1.f / 1024.f);
  float var = ss * (1.f / 1024.f) - mu * mu;
  float rinv = rsqrtf(var + 1e-5f);
  float4 gmv = *(const float4*)(gamma + t * 4);
  float4 bev = *(const float4*)(beta + t * 4);
  float4 o;
  o.x = (h0 - mu) * rinv * gmv.x + bev.x;
  o.y = (h1 - mu) * rinv * gmv.y + bev.y;
  o.z = (h2 - mu) * rinv * gmv.z + bev.z;
  o.w = (h3 - mu) * rinv * gmv.w + bev.w;
  *(float4*)(op + t * 4) = o;
}

// ---------------------------------------------------------------------------
extern "C" void kernel_launch(void* const* d_in, const int* in_sizes, int n_in,
                              void* d_out, int out_size, void* d_ws, size_t ws_size,
                              hipStream_t stream) {
  const float* x = (const float*)d_in[0];
  const float* y = (const float*)d_in[1];
  const float* Wq = (const float*)d_in[2];
  const float* Wk = (const float*)d_in[3];
  const float* Wv = (const float*)d_in[4];
  const float* bq = (const float*)d_in[5];
  const float* bk = (const float*)d_in[6];
  const float* bv = (const float*)d_in[7];
  const float* gamma = (const float*)d_in[8];
  const float* beta = (const float*)d_in[9];
  float* out = (float*)d_out;

  char* ws = (char*)d_ws;
  u16* xT = (u16*)(ws + 0);               // 8388608 B
  u16* yT = (u16*)(ws + 8388608);         // 8388608 B
  u16* WT = (u16*)(ws + 16777216);        // 6291456 B
  u16* Qb = (u16*)(ws + 23068672);        // 8388608 B
  u16* Kb = (u16*)(ws + 31457280);        // 8388608 B
  u16* VT = (u16*)(ws + 39845888);        // 8388608 B
  u16* att = (u16*)(ws + 48234496);       // 8388608 B (end 56623104)

  transpose_xy<<<dim3(Ln / 64, Cn / 64, 4), dim3(256), 0, stream>>>(x, y, xT, yT);
  transpose_w<<<dim3(Cn / 64, Hn, 3), dim3(256), 0, stream>>>(Wq, Wk, Wv, WT);
  gemm_qkv3<<<dim3(Ln / 128, 24, Bn), dim3(256), 0, stream>>>(xT, yT, WT, bq, bk, bv, Qb, Kb, VT);
  flash_attn<<<dim3(Ln / 64, Hn, Bn), dim3(256), 0, stream>>>(Qb, Kb, VT, att);
  ln_kernel<<<dim3(Bn * Ln), dim3(256), 0, stream>>>(att, xT, gamma, beta, out);
}